// Round 2
// baseline (55764.215 us; speedup 1.0000x reference)
//
#include <hip/hip_runtime.h>
#include <cstdint>
#include <cstddef>

#define TPB 256

static inline int cdiv(long long a, int b){ return (int)((a + (long long)b - 1) / b); }

// ---------------- kernels ----------------

__global__ void k_deg_count(const int* __restrict__ row, float* __restrict__ deg, int E){
  int e = blockIdx.x*blockDim.x + threadIdx.x;
  if (e < E) atomicAdd(&deg[row[e]], 1.0f);
}

__global__ void k_edge_norm(const int* __restrict__ ei, const float* __restrict__ deg,
                            float* __restrict__ w, int E){
  int e = blockIdx.x*blockDim.x + threadIdx.x;
  if (e >= E) return;
  float dr = deg[ei[e]];
  float dc = deg[ei[E + e]];
  float a = dr > 0.f ? rsqrtf(dr) : 0.f;
  float b = dc > 0.f ? rsqrtf(dc) : 0.f;
  w[e] = a * b;
}

// x: [2,16,N,3] -> h: [32,N,6], g = b*16+t, phase doubling with cos/sin(2*pi*t/16)
__global__ void k_phase_enc(const float* __restrict__ x, float* __restrict__ h, int N){
  int i = blockIdx.x*blockDim.x + threadIdx.x;
  if (i >= 32*N) return;
  int n = i % N, g = i / N;
  int t = g & 15;
  float th = 6.283185307179586f * (float)t / 16.0f;
  float s, c;
  sincosf(th, &s, &c);
  const float* xr = x + ((size_t)g*N + n)*3;
  float* hr = h + ((size_t)g*N + n)*6;
  float a0 = xr[0], a1 = xr[1], a2 = xr[2];
  hr[0] = a0*c; hr[1] = a1*c; hr[2] = a2*c;
  hr[3] = a0*s; hr[4] = a1*s; hr[5] = a2*s;
}

// scatter prop: P[g, dst, f] += w[e] * X[g, src, f]
__global__ void k_prop(const int* __restrict__ ei, const float* __restrict__ w,
                       const float* __restrict__ X, float* __restrict__ P,
                       int E, int G, int N, int F){
  int idx = blockIdx.x*blockDim.x + threadIdx.x;
  if (idx >= E*G) return;
  int e = idx % E, g = idx / E;
  int src = ei[e], dst = ei[E + e];
  float we = w[e];
  const float* xr = X + ((size_t)g*N + src)*F;
  float* pr = P + ((size_t)g*N + dst)*F;
  for (int f = 0; f < F; ++f) atomicAdd(&pr[f], we * xr[f]);
}

// out[i,:Fout] (init: bias +)(else +=) T[i,:Fin] @ W[Fin,Fout]; optional relu at the end
__global__ void k_term(const float* __restrict__ T, const float* __restrict__ W,
                       const float* __restrict__ bias, float* __restrict__ out,
                       int GN, int Fin, int Fout, int init, int relu){
  int i = blockIdx.x*blockDim.x + threadIdx.x;
  if (i >= GN) return;
  const float* tr = T + (size_t)i*Fin;
  float row[32];
  for (int f = 0; f < Fin; ++f) row[f] = tr[f];
  float* orow = out + (size_t)i*Fout;
  for (int fo = 0; fo < Fout; ++fo){
    float acc = init ? (bias ? bias[fo] : 0.f) : orow[fo];
    for (int fi = 0; fi < Fin; ++fi) acc = fmaf(row[fi], W[fi*Fout + fo], acc);
    if (relu) acc = fmaxf(acc, 0.f);
    orow[fo] = acc;
  }
}

// S = 2*S - T0
__global__ void k_combine(float* __restrict__ S, const float* __restrict__ T0, int n){
  int i = blockIdx.x*blockDim.x + threadIdx.x;
  if (i < n) S[i] = 2.f*S[i] - T0[i];
}

// out[g,n,f] = sum_k w[n,k] * X[g, idx[n,k], f]
__global__ void k_pool(const float* __restrict__ X, const int* __restrict__ idx,
                       const float* __restrict__ w, float* __restrict__ out,
                       int G, int Nin, int Nout, int F){
  int i = blockIdx.x*blockDim.x + threadIdx.x;
  if (i >= G*Nout) return;
  int n = i % Nout, g = i / Nout;
  int i0 = idx[n*3+0], i1 = idx[n*3+1], i2 = idx[n*3+2];
  float w0 = w[n*3+0], w1 = w[n*3+1], w2 = w[n*3+2];
  const float* b = X + (size_t)g*Nin*F;
  float* o = out + ((size_t)g*Nout + n)*F;
  for (int f = 0; f < F; ++f)
    o[f] = fmaf(w0, b[(size_t)i0*F + f], fmaf(w1, b[(size_t)i1*F + f], w2 * b[(size_t)i2*F + f]));
}

// mu[g,z] = h[g,:2048] . mu_W[z,:2048] + mu_b[z]   (g over 32, z over 48)
__global__ void k_mu(const float* __restrict__ h, const float* __restrict__ W,
                     const float* __restrict__ b, float* __restrict__ mu){
  int i = blockIdx.x*blockDim.x + threadIdx.x;
  if (i >= 32*48) return;
  int z = i % 48, g = i / 48;
  const float* hr = h + (size_t)g*2048;
  const float* wr = W + (size_t)z*2048;
  float acc = b[z];
  for (int f = 0; f < 2048; ++f) acc = fmaf(hr[f], wr[f], acc);
  mu[i] = acc;
}

// faithful permuted mean: muc[b'] = (1/16) sum_{b=0,1} sum_{t=8b'..8b'+7} mu[b,t]
__global__ void k_mucs(const float* __restrict__ mu, float* __restrict__ muc,
                       float* __restrict__ mus, float* __restrict__ out){
  int i = blockIdx.x*blockDim.x + threadIdx.x;
  if (i >= 96) return;
  int z = i % 48, bp = i / 48;
  float acc = 0.f;
  for (int b = 0; b < 2; ++b)
    for (int t = 8*bp; t < 8*bp + 8; ++t)
      acc += mu[(b*16 + t)*48 + z];
  acc *= (1.f/16.f);
  if (z < 32){ muc[bp*32 + z] = acc; out[bp*32 + z] = acc; }
  else       { mus[bp*16 + (z-32)] = acc; out[64 + bp*16 + (z-32)] = acc; }
}

// zin[g=b*16+t, 0:32]=muc[b]; [32:48]=mus[b]*cos(th_t); [48:64]=mus[b]*sin(th_t)
__global__ void k_zin(const float* __restrict__ muc, const float* __restrict__ mus,
                      float* __restrict__ zin){
  int i = blockIdx.x*blockDim.x + threadIdx.x;
  if (i >= 32*64) return;
  int c = i % 64, g = i / 64;
  int b = g / 16, t = g % 16;
  float v;
  if (c < 32){
    v = muc[b*32 + c];
  } else {
    float th = 6.283185307179586f * (float)t / 16.0f;
    int k = c - 32;
    int kk = (k < 16) ? k : (k - 16);
    float m = mus[b*16 + kk];
    v = (k < 16) ? m * cosf(th) : m * sinf(th);
  }
  zin[i] = v;
}

// y[g,f] = z[g,:Z] . W[f,:Z] + b[f]  (W row-major [2048, Z]); optional relu
__global__ void k_lin(const float* __restrict__ z, const float* __restrict__ W,
                      const float* __restrict__ b, float* __restrict__ y,
                      int G, int Z, int relu){
  int i = blockIdx.x*blockDim.x + threadIdx.x;
  if (i >= G*2048) return;
  int f = i % 2048, g = i / 2048;
  const float* zr = z + (size_t)g*Z;
  const float* wr = W + (size_t)f*Z;
  float acc = b[f];
  for (int k = 0; k < Z; ++k) acc = fmaf(zr[k], wr[k], acc);
  if (relu) acc = fmaxf(acc, 0.f);
  y[i] = acc;
}

// s_t[g,n,c] = s_avg[b= g/16, n, c] + ds[g,n,c]
__global__ void k_st(const float* __restrict__ savg, const float* __restrict__ ds,
                     float* __restrict__ st, int N){
  int i = blockIdx.x*blockDim.x + threadIdx.x;
  if (i >= 32*N*3) return;
  int c = i % (N*3);
  int g = i / (N*3);
  int b = g >> 4;
  st[i] = savg[(size_t)b*N*3 + c] + ds[i];
}

// ---------------- host orchestration ----------------

// Chebyshev conv, K=6. Trashes X, T1, S. out must be distinct from X/T1/S.
static void run_cheb(hipStream_t s, const int* ei, const float* nrm, int E, int N, int G,
                     float* X, float* T1, float* S, float* out,
                     const float* W6, const float* bias, int Fin, int Fout, bool relu){
  long long GN = (long long)G * N;
  long long EG = (long long)E * G;
  // k=0: out = X @ W0 (+ bias)
  k_term<<<cdiv(GN,TPB),TPB,0,s>>>(X, W6, bias, out, (int)GN, Fin, Fout, 1, 0);
  // T1 = prop(X); out += T1 @ W1
  hipMemsetAsync(T1, 0, (size_t)GN*Fin*sizeof(float), s);
  k_prop<<<cdiv(EG,TPB),TPB,0,s>>>(ei, nrm, X, T1, E, G, N, Fin);
  k_term<<<cdiv(GN,TPB),TPB,0,s>>>(T1, W6 + (size_t)Fin*Fout, nullptr, out, (int)GN, Fin, Fout, 0, 0);
  float* t0 = X; float* t1 = T1; float* sp = S;
  for (int k = 2; k < 6; ++k){
    hipMemsetAsync(sp, 0, (size_t)GN*Fin*sizeof(float), s);
    k_prop<<<cdiv(EG,TPB),TPB,0,s>>>(ei, nrm, t1, sp, E, G, N, Fin);
    k_combine<<<cdiv(GN*Fin,TPB),TPB,0,s>>>(sp, t0, (int)(GN*Fin));
    int last = (k == 5) ? 1 : 0;
    k_term<<<cdiv(GN,TPB),TPB,0,s>>>(sp, W6 + (size_t)k*Fin*Fout, nullptr, out,
                                     (int)GN, Fin, Fout, 0, (last && relu) ? 1 : 0);
    float* tmp = t0; t0 = t1; t1 = sp; sp = tmp;
  }
}

// shared decoder: z [G, Z] -> out_final [G, 16384, 3]
// out_final must be distinct from B0, B1, B2.
static void run_dec(hipStream_t s, int G, const float* z, int Z,
                    const float* lW, const float* lb, bool relu_first,
                    const float* const* W, const float* const* Bc,  // W[0..3], Bc[0..2]
                    const int* const* ei, float* const* nrm, const int* Es,
                    const int* const* us_i, const float* const* us_w,
                    float* B0, float* B1, float* B2, float* B3, float* out_final){
  k_lin<<<cdiv((long long)G*2048,TPB),TPB,0,s>>>(z, lW, lb, B0, G, Z, relu_first ? 1 : 0);
  // i=0: lvl 3: 64 -> 256, cheb(ei3) 32->16
  k_pool<<<cdiv((long long)G*256,TPB),TPB,0,s>>>(B0, us_i[3], us_w[3], B1, G, 64, 256, 32);
  run_cheb(s, ei[3], nrm[3], Es[3], 256, G, B1, B0, B2, B3, W[0], Bc[0], 32, 16, true);
  // i=1: lvl 2: 256 -> 1024, cheb(ei2) 16->16
  k_pool<<<cdiv((long long)G*1024,TPB),TPB,0,s>>>(B3, us_i[2], us_w[2], B0, G, 256, 1024, 16);
  run_cheb(s, ei[2], nrm[2], Es[2], 1024, G, B0, B1, B2, B3, W[1], Bc[1], 16, 16, true);
  // i=2: lvl 1: 1024 -> 4096, cheb(ei1) 16->16
  k_pool<<<cdiv((long long)G*4096,TPB),TPB,0,s>>>(B3, us_i[1], us_w[1], B0, G, 1024, 4096, 16);
  run_cheb(s, ei[1], nrm[1], Es[1], 4096, G, B0, B1, B2, B3, W[2], Bc[2], 16, 16, true);
  // final: 4096 -> 16384, cheb(ei4) 16->3, no bias, no relu -> out_final
  k_pool<<<cdiv((long long)G*16384,TPB),TPB,0,s>>>(B3, us_i[0], us_w[0], B0, G, 4096, 16384, 16);
  run_cheb(s, ei[4], nrm[4], Es[4], 16384, G, B0, B1, B2, out_final, W[3], nullptr, 16, 3, false);
}

extern "C" void kernel_launch(void* const* d_in, const int* in_sizes, int n_in,
                              void* d_out, int out_size, void* d_ws, size_t ws_size,
                              hipStream_t stream){
  const float* x = (const float*)d_in[0];
  const float* encW[4] = {(const float*)d_in[1],(const float*)d_in[3],(const float*)d_in[5],(const float*)d_in[7]};
  const float* encB[4] = {(const float*)d_in[2],(const float*)d_in[4],(const float*)d_in[6],(const float*)d_in[8]};
  const float* ccW[4]  = {(const float*)d_in[9],(const float*)d_in[11],(const float*)d_in[13],(const float*)d_in[15]};
  const float* ccB[3]  = {(const float*)d_in[10],(const float*)d_in[12],(const float*)d_in[14]};
  const float* csW[4]  = {(const float*)d_in[16],(const float*)d_in[18],(const float*)d_in[20],(const float*)d_in[22]};
  const float* csB[3]  = {(const float*)d_in[17],(const float*)d_in[19],(const float*)d_in[21]};
  const float* muW  = (const float*)d_in[23]; const float* muB  = (const float*)d_in[24];
  const float* lincW = (const float*)d_in[25]; const float* lincB = (const float*)d_in[26];
  const float* linsW = (const float*)d_in[27]; const float* linsB = (const float*)d_in[28];
  const int* ei[5] = {(const int*)d_in[29],(const int*)d_in[30],(const int*)d_in[31],
                      (const int*)d_in[32],(const int*)d_in[33]};
  const int* ds_i[4]; const float* ds_w[4]; const int* us_i[4]; const float* us_w[4];
  for (int l = 0; l < 4; ++l){
    ds_i[l] = (const int*)d_in[34 + 4*l]; ds_w[l] = (const float*)d_in[35 + 4*l];
    us_i[l] = (const int*)d_in[36 + 4*l]; us_w[l] = (const float*)d_in[37 + 4*l];
  }

  float* ws = (float*)d_ws;
  const size_t BIG = 8388608;   // 32*16384*16 floats
  float* B0 = ws + 0*BIG;
  float* B1 = ws + 1*BIG;
  float* B2 = ws + 2*BIG;
  float* B3 = ws + 3*BIG;
  size_t off = 4*BIG;
  int Es[5] = {196608, 49152, 12288, 3072, 196608};
  int Nn[5] = {16384, 4096, 1024, 256, 16384};    // norm node counts (lvl 4 uses N0)
  float* nrm[5];
  for (int l = 0; l < 5; ++l){ nrm[l] = ws + off; off += (size_t)Es[l]; }
  float* deg = ws + off; off += 16384;
  float* hmu = ws + off; off += (size_t)32*2048;
  float* mu  = ws + off; off += (size_t)32*48;
  float* muc = ws + off; off += 64;
  float* mus = ws + off; off += 32;
  float* zin = ws + off; off += (size_t)32*64;
  float* outp = (float*)d_out;
  float* out_savg = outp + 96;         // [2,16384,3]
  float* out_st   = outp + 96 + 98304; // [2,16,16384,3]

  // ---- edge norms per level ----
  for (int l = 0; l < 5; ++l){
    hipMemsetAsync(deg, 0, (size_t)Nn[l]*sizeof(float), stream);
    k_deg_count<<<cdiv(Es[l],TPB),TPB,0,stream>>>(ei[l], deg, Es[l]);
    k_edge_norm<<<cdiv(Es[l],TPB),TPB,0,stream>>>(ei[l], deg, nrm[l], Es[l]);
  }

  // ---- encoder ----
  k_phase_enc<<<cdiv((long long)32*16384,TPB),TPB,0,stream>>>(x, B0, 16384);
  int NSl[5] = {16384, 4096, 1024, 256, 64};
  int Fi[4] = {6,16,16,16}, Fo[4] = {16,16,16,32};
  for (int l = 0; l < 4; ++l){
    run_cheb(stream, ei[l], nrm[l], Es[l], NSl[l], 32, B0, B1, B2, B3, encW[l], encB[l], Fi[l], Fo[l], true);
    float* dst = (l == 3) ? hmu : B0;
    k_pool<<<cdiv((long long)32*NSl[l+1],TPB),TPB,0,stream>>>(B3, ds_i[l], ds_w[l], dst, 32, NSl[l], NSl[l+1], Fo[l]);
  }

  // ---- latent ----
  k_mu<<<cdiv(32*48,TPB),TPB,0,stream>>>(hmu, muW, muB, mu);
  k_mucs<<<1,128,0,stream>>>(mu, muc, mus, outp);

  // ---- decoder c (G=2) -> s_avg straight into d_out ----
  run_dec(stream, 2, muc, 32, lincW, lincB, false, ccW, ccB,
          ei, nrm, Es, us_i, us_w, B0, B1, B2, B3, out_savg);

  // ---- decoder s (G=32) -> ds_t into B3 ----
  k_zin<<<cdiv(32*64,TPB),TPB,0,stream>>>(muc, mus, zin);
  run_dec(stream, 32, zin, 64, linsW, linsB, true, csW, csB,
          ei, nrm, Es, us_i, us_w, B0, B1, B2, B3, B3);

  // ---- s_t = s_avg + ds_t ----
  k_st<<<cdiv((long long)32*16384*3,TPB),TPB,0,stream>>>(out_savg, B3, out_st, 16384);

  (void)in_sizes; (void)n_in; (void)out_size; (void)ws_size;
}

// Round 3
// 4883.439 us; speedup vs baseline: 11.4190x; 11.4190x over previous
//
#include <hip/hip_runtime.h>
#include <cstdint>
#include <cstddef>

#define TPB 256

static inline int cdiv(long long a, int b){ return (int)((a + (long long)b - 1) / b); }

// ---------------- CSR build ----------------

// count src-degree (for norm) and dst-degree (for CSR) in one pass
__global__ void k_degs(const int* __restrict__ ei, int* __restrict__ rowdeg,
                       int* __restrict__ dstdeg, int E){
  int e = blockIdx.x*blockDim.x + threadIdx.x;
  if (e >= E) return;
  atomicAdd(&rowdeg[ei[e]], 1);
  atomicAdd(&dstdeg[ei[E + e]], 1);
}

__global__ void k_dis(const int* __restrict__ rowdeg, float* __restrict__ dis, int N){
  int n = blockIdx.x*blockDim.x + threadIdx.x;
  if (n >= N) return;
  int d = rowdeg[n];
  dis[n] = d > 0 ? rsqrtf((float)d) : 0.f;
}

// single-block exclusive scan of cnt[0..N) -> rp[0..N], copy into cursor
__global__ void k_scan(const int* __restrict__ cnt, int* __restrict__ rp,
                       int* __restrict__ cursor, int N){
  __shared__ int part[257];
  int tid = threadIdx.x;
  int chunk = (N + 255) / 256;
  int lo = tid*chunk; if (lo > N) lo = N;
  int hi = lo + chunk; if (hi > N) hi = N;
  int s = 0;
  for (int i = lo; i < hi; ++i) s += cnt[i];
  part[tid+1] = s;
  if (tid == 0) part[0] = 0;
  __syncthreads();
  if (tid == 0){ for (int i = 1; i <= 256; ++i) part[i] += part[i-1]; }
  __syncthreads();
  int run = part[tid];
  for (int i = lo; i < hi; ++i){ rp[i] = run; cursor[i] = run; run += cnt[i]; }
  if (tid == 0) rp[N] = part[256];
}

// fill CSR: srcs[pos]=src, w[pos]=dis[src]*dis[dst]
__global__ void k_fill(const int* __restrict__ ei, const float* __restrict__ dis,
                       int* __restrict__ cursor, int* __restrict__ srcs,
                       float* __restrict__ wcsr, int E){
  int e = blockIdx.x*blockDim.x + threadIdx.x;
  if (e >= E) return;
  int src = ei[e], dst = ei[E + e];
  int pos = atomicAdd(&cursor[dst], 1);
  srcs[pos] = src;
  wcsr[pos] = dis[src] * dis[dst];
}

// ---------------- model kernels ----------------

// x: [2,16,N,3] -> h: [32,N,6]
__global__ void k_phase_enc(const float* __restrict__ x, float* __restrict__ h, int N){
  int i = blockIdx.x*blockDim.x + threadIdx.x;
  if (i >= 32*N) return;
  int n = i % N, g = i / N;
  int t = g & 15;
  float th = 6.283185307179586f * (float)t / 16.0f;
  float s, c;
  sincosf(th, &s, &c);
  const float* xr = x + ((size_t)g*N + n)*3;
  float* hr = h + ((size_t)g*N + n)*6;
  float a0 = xr[0], a1 = xr[1], a2 = xr[2];
  hr[0] = a0*c; hr[1] = a1*c; hr[2] = a2*c;
  hr[3] = a0*s; hr[4] = a1*s; hr[5] = a2*s;
}

// gather prop: P[g,n,f] = sum_j w[j]*X[g,srcs[j],f], j in [rp[n],rp[n+1])
// if T0 != nullptr: P = 2*P - T0  (Chebyshev combine fused)
__global__ void k_gather(const int* __restrict__ rp, const int* __restrict__ srcs,
                         const float* __restrict__ wcsr, const float* __restrict__ X,
                         const float* __restrict__ T0, float* __restrict__ P,
                         int G, int N, int F){
  int idx = blockIdx.x*blockDim.x + threadIdx.x;
  if (idx >= G*N*F) return;
  int f = idx % F;
  int n = (idx / F) % N;
  int g = idx / (F*N);
  const float* xb = X + (size_t)g*N*F + f;
  int j0 = rp[n], j1 = rp[n+1];
  float acc = 0.f;
  for (int j = j0; j < j1; ++j)
    acc = fmaf(wcsr[j], xb[(size_t)srcs[j]*F], acc);
  if (T0) acc = 2.f*acc - T0[idx];
  P[idx] = acc;
}

// out[i,:Fout] (init: bias +)(else +=) T[i,:Fin] @ W[Fin,Fout]; optional relu
__global__ void k_term(const float* __restrict__ T, const float* __restrict__ W,
                       const float* __restrict__ bias, float* __restrict__ out,
                       int GN, int Fin, int Fout, int init, int relu){
  int i = blockIdx.x*blockDim.x + threadIdx.x;
  if (i >= GN) return;
  const float* tr = T + (size_t)i*Fin;
  float row[32];
  for (int f = 0; f < Fin; ++f) row[f] = tr[f];
  float* orow = out + (size_t)i*Fout;
  for (int fo = 0; fo < Fout; ++fo){
    float acc = init ? (bias ? bias[fo] : 0.f) : orow[fo];
    for (int fi = 0; fi < Fin; ++fi) acc = fmaf(row[fi], W[fi*Fout + fo], acc);
    if (relu) acc = fmaxf(acc, 0.f);
    orow[fo] = acc;
  }
}

// out[g,n,f] = sum_k w[n,k] * X[g, idx[n,k], f]
__global__ void k_pool(const float* __restrict__ X, const int* __restrict__ idx,
                       const float* __restrict__ w, float* __restrict__ out,
                       int G, int Nin, int Nout, int F){
  int i = blockIdx.x*blockDim.x + threadIdx.x;
  if (i >= G*Nout) return;
  int n = i % Nout, g = i / Nout;
  int i0 = idx[n*3+0], i1 = idx[n*3+1], i2 = idx[n*3+2];
  float w0 = w[n*3+0], w1 = w[n*3+1], w2 = w[n*3+2];
  const float* b = X + (size_t)g*Nin*F;
  float* o = out + ((size_t)g*Nout + n)*F;
  for (int f = 0; f < F; ++f)
    o[f] = fmaf(w0, b[(size_t)i0*F + f], fmaf(w1, b[(size_t)i1*F + f], w2 * b[(size_t)i2*F + f]));
}

// mu[g,z] = h[g,:2048] . mu_W[z,:2048] + mu_b[z]
__global__ void k_mu(const float* __restrict__ h, const float* __restrict__ W,
                     const float* __restrict__ b, float* __restrict__ mu){
  int i = blockIdx.x*blockDim.x + threadIdx.x;
  if (i >= 32*48) return;
  int z = i % 48, g = i / 48;
  const float* hr = h + (size_t)g*2048;
  const float* wr = W + (size_t)z*2048;
  float acc = b[z];
  for (int f = 0; f < 2048; ++f) acc = fmaf(hr[f], wr[f], acc);
  mu[i] = acc;
}

// faithful permuted mean
__global__ void k_mucs(const float* __restrict__ mu, float* __restrict__ muc,
                       float* __restrict__ mus, float* __restrict__ out){
  int i = blockIdx.x*blockDim.x + threadIdx.x;
  if (i >= 96) return;
  int z = i % 48, bp = i / 48;
  float acc = 0.f;
  for (int b = 0; b < 2; ++b)
    for (int t = 8*bp; t < 8*bp + 8; ++t)
      acc += mu[(b*16 + t)*48 + z];
  acc *= (1.f/16.f);
  if (z < 32){ muc[bp*32 + z] = acc; out[bp*32 + z] = acc; }
  else       { mus[bp*16 + (z-32)] = acc; out[64 + bp*16 + (z-32)] = acc; }
}

__global__ void k_zin(const float* __restrict__ muc, const float* __restrict__ mus,
                      float* __restrict__ zin){
  int i = blockIdx.x*blockDim.x + threadIdx.x;
  if (i >= 32*64) return;
  int c = i % 64, g = i / 64;
  int b = g / 16, t = g % 16;
  float v;
  if (c < 32){
    v = muc[b*32 + c];
  } else {
    float th = 6.283185307179586f * (float)t / 16.0f;
    int k = c - 32;
    int kk = (k < 16) ? k : (k - 16);
    float m = mus[b*16 + kk];
    v = (k < 16) ? m * cosf(th) : m * sinf(th);
  }
  zin[i] = v;
}

// y[g,f] = z[g,:Z] . W[f,:Z] + b[f]; optional relu
__global__ void k_lin(const float* __restrict__ z, const float* __restrict__ W,
                      const float* __restrict__ b, float* __restrict__ y,
                      int G, int Z, int relu){
  int i = blockIdx.x*blockDim.x + threadIdx.x;
  if (i >= G*2048) return;
  int f = i % 2048, g = i / 2048;
  const float* zr = z + (size_t)g*Z;
  const float* wr = W + (size_t)f*Z;
  float acc = b[f];
  for (int k = 0; k < Z; ++k) acc = fmaf(zr[k], wr[k], acc);
  if (relu) acc = fmaxf(acc, 0.f);
  y[i] = acc;
}

__global__ void k_st(const float* __restrict__ savg, const float* __restrict__ ds,
                     float* __restrict__ st, int N){
  int i = blockIdx.x*blockDim.x + threadIdx.x;
  if (i >= 32*N*3) return;
  int c = i % (N*3);
  int g = i / (N*3);
  int b = g >> 4;
  st[i] = savg[(size_t)b*N*3 + c] + ds[i];
}

// ---------------- host orchestration ----------------

struct Csr { const int* rp; const int* srcs; const float* w; };

// Chebyshev conv, K=6, CSR gather. Trashes X, T1, S. out distinct from X/T1/S.
static void run_cheb(hipStream_t s, const Csr& A, int N, int G,
                     float* X, float* T1, float* S, float* out,
                     const float* W6, const float* bias, int Fin, int Fout, bool relu){
  long long GN = (long long)G * N;
  long long GNF = GN * Fin;
  // k=0: out = X @ W0 (+ bias)
  k_term<<<cdiv(GN,TPB),TPB,0,s>>>(X, W6, bias, out, (int)GN, Fin, Fout, 1, 0);
  // T1 = prop(X); out += T1 @ W1
  k_gather<<<cdiv(GNF,TPB),TPB,0,s>>>(A.rp, A.srcs, A.w, X, nullptr, T1, G, N, Fin);
  k_term<<<cdiv(GN,TPB),TPB,0,s>>>(T1, W6 + (size_t)Fin*Fout, nullptr, out, (int)GN, Fin, Fout, 0, 0);
  float* t0 = X; float* t1 = T1; float* sp = S;
  for (int k = 2; k < 6; ++k){
    // sp = 2*prop(t1) - t0
    k_gather<<<cdiv(GNF,TPB),TPB,0,s>>>(A.rp, A.srcs, A.w, t1, t0, sp, G, N, Fin);
    int last = (k == 5) ? 1 : 0;
    k_term<<<cdiv(GN,TPB),TPB,0,s>>>(sp, W6 + (size_t)k*Fin*Fout, nullptr, out,
                                     (int)GN, Fin, Fout, 0, (last && relu) ? 1 : 0);
    float* tmp = t0; t0 = t1; t1 = sp; sp = tmp;
  }
}

// shared decoder: z [G, Z] -> out_final [G, 16384, 3]; out_final distinct from B0/B1/B2
static void run_dec(hipStream_t s, int G, const float* z, int Z,
                    const float* lW, const float* lb, bool relu_first,
                    const float* const* W, const float* const* Bc,
                    const Csr* A, const int* const* us_i, const float* const* us_w,
                    float* B0, float* B1, float* B2, float* B3, float* out_final){
  k_lin<<<cdiv((long long)G*2048,TPB),TPB,0,s>>>(z, lW, lb, B0, G, Z, relu_first ? 1 : 0);
  k_pool<<<cdiv((long long)G*256,TPB),TPB,0,s>>>(B0, us_i[3], us_w[3], B1, G, 64, 256, 32);
  run_cheb(s, A[3], 256, G, B1, B0, B2, B3, W[0], Bc[0], 32, 16, true);
  k_pool<<<cdiv((long long)G*1024,TPB),TPB,0,s>>>(B3, us_i[2], us_w[2], B0, G, 256, 1024, 16);
  run_cheb(s, A[2], 1024, G, B0, B1, B2, B3, W[1], Bc[1], 16, 16, true);
  k_pool<<<cdiv((long long)G*4096,TPB),TPB,0,s>>>(B3, us_i[1], us_w[1], B0, G, 1024, 4096, 16);
  run_cheb(s, A[1], 4096, G, B0, B1, B2, B3, W[2], Bc[2], 16, 16, true);
  k_pool<<<cdiv((long long)G*16384,TPB),TPB,0,s>>>(B3, us_i[0], us_w[0], B0, G, 4096, 16384, 16);
  run_cheb(s, A[4], 16384, G, B0, B1, B2, out_final, W[3], nullptr, 16, 3, false);
}

extern "C" void kernel_launch(void* const* d_in, const int* in_sizes, int n_in,
                              void* d_out, int out_size, void* d_ws, size_t ws_size,
                              hipStream_t stream){
  const float* x = (const float*)d_in[0];
  const float* encW[4] = {(const float*)d_in[1],(const float*)d_in[3],(const float*)d_in[5],(const float*)d_in[7]};
  const float* encB[4] = {(const float*)d_in[2],(const float*)d_in[4],(const float*)d_in[6],(const float*)d_in[8]};
  const float* ccW[4]  = {(const float*)d_in[9],(const float*)d_in[11],(const float*)d_in[13],(const float*)d_in[15]};
  const float* ccB[3]  = {(const float*)d_in[10],(const float*)d_in[12],(const float*)d_in[14]};
  const float* csW[4]  = {(const float*)d_in[16],(const float*)d_in[18],(const float*)d_in[20],(const float*)d_in[22]};
  const float* csB[3]  = {(const float*)d_in[17],(const float*)d_in[19],(const float*)d_in[21]};
  const float* muW  = (const float*)d_in[23]; const float* muB  = (const float*)d_in[24];
  const float* lincW = (const float*)d_in[25]; const float* lincB = (const float*)d_in[26];
  const float* linsW = (const float*)d_in[27]; const float* linsB = (const float*)d_in[28];
  const int* ei[5] = {(const int*)d_in[29],(const int*)d_in[30],(const int*)d_in[31],
                      (const int*)d_in[32],(const int*)d_in[33]};
  const int* ds_i[4]; const float* ds_w[4]; const int* us_i[4]; const float* us_w[4];
  for (int l = 0; l < 4; ++l){
    ds_i[l] = (const int*)d_in[34 + 4*l]; ds_w[l] = (const float*)d_in[35 + 4*l];
    us_i[l] = (const int*)d_in[36 + 4*l]; us_w[l] = (const float*)d_in[37 + 4*l];
  }

  float* ws = (float*)d_ws;
  const size_t BIG = 8388608;   // 32*16384*16 floats
  float* B0 = ws + 0*BIG;
  float* B1 = ws + 1*BIG;
  float* B2 = ws + 2*BIG;
  float* B3 = ws + 3*BIG;
  size_t off = 4*BIG;

  int Es[5] = {196608, 49152, 12288, 3072, 196608};
  int Nn[5] = {16384, 4096, 1024, 256, 16384};  // graph node counts (lvl4 = N0)

  // CSR storage per level
  int* rp[5]; int* cursor[5]; int* srcs[5]; float* wcsr[5];
  for (int l = 0; l < 5; ++l){
    rp[l]     = (int*)(ws + off); off += (size_t)Nn[l] + 1;
    cursor[l] = (int*)(ws + off); off += (size_t)Nn[l] + 1;
    srcs[l]   = (int*)(ws + off); off += (size_t)Es[l];
    wcsr[l]   =        ws + off;  off += (size_t)Es[l];
  }
  int* rowdeg = (int*)(ws + off); off += 16384;
  int* dstdeg = (int*)(ws + off); off += 16384;
  float* dis  = ws + off; off += 16384;
  float* hmu = ws + off; off += (size_t)32*2048;
  float* mu  = ws + off; off += (size_t)32*48;
  float* muc = ws + off; off += 64;
  float* mus = ws + off; off += 32;
  float* zin = ws + off; off += (size_t)32*64;

  float* outp = (float*)d_out;
  float* out_savg = outp + 96;         // [2,16384,3]
  float* out_st   = outp + 96 + 98304; // [2,16,16384,3]

  // ---- CSR build per level ----
  for (int l = 0; l < 5; ++l){
    hipMemsetAsync(rowdeg, 0, (size_t)Nn[l]*sizeof(int), stream);
    hipMemsetAsync(dstdeg, 0, (size_t)Nn[l]*sizeof(int), stream);
    k_degs<<<cdiv(Es[l],TPB),TPB,0,stream>>>(ei[l], rowdeg, dstdeg, Es[l]);
    k_dis<<<cdiv(Nn[l],TPB),TPB,0,stream>>>(rowdeg, dis, Nn[l]);
    k_scan<<<1,256,0,stream>>>(dstdeg, rp[l], cursor[l], Nn[l]);
    k_fill<<<cdiv(Es[l],TPB),TPB,0,stream>>>(ei[l], dis, cursor[l], srcs[l], wcsr[l], Es[l]);
  }
  Csr A[5];
  for (int l = 0; l < 5; ++l) A[l] = Csr{rp[l], srcs[l], wcsr[l]};

  // ---- encoder ----
  k_phase_enc<<<cdiv((long long)32*16384,TPB),TPB,0,stream>>>(x, B0, 16384);
  int NSl[5] = {16384, 4096, 1024, 256, 64};
  int Fi[4] = {6,16,16,16}, Fo[4] = {16,16,16,32};
  for (int l = 0; l < 4; ++l){
    run_cheb(stream, A[l], NSl[l], 32, B0, B1, B2, B3, encW[l], encB[l], Fi[l], Fo[l], true);
    float* dst = (l == 3) ? hmu : B0;
    k_pool<<<cdiv((long long)32*NSl[l+1],TPB),TPB,0,stream>>>(B3, ds_i[l], ds_w[l], dst, 32, NSl[l], NSl[l+1], Fo[l]);
  }

  // ---- latent ----
  k_mu<<<cdiv(32*48,TPB),TPB,0,stream>>>(hmu, muW, muB, mu);
  k_mucs<<<1,128,0,stream>>>(mu, muc, mus, outp);

  // ---- decoder c (G=2) -> s_avg in d_out ----
  run_dec(stream, 2, muc, 32, lincW, lincB, false, ccW, ccB,
          A, us_i, us_w, B0, B1, B2, B3, out_savg);

  // ---- decoder s (G=32) -> ds_t in B3 ----
  k_zin<<<cdiv(32*64,TPB),TPB,0,stream>>>(muc, mus, zin);
  run_dec(stream, 32, zin, 64, linsW, linsB, true, csW, csB,
          A, us_i, us_w, B0, B1, B2, B3, B3);

  // ---- s_t = s_avg + ds_t ----
  k_st<<<cdiv((long long)32*16384*3,TPB),TPB,0,stream>>>(out_savg, B3, out_st, 16384);

  (void)in_sizes; (void)n_in; (void)out_size; (void)ws_size;
}

// Round 4
// 2452.200 us; speedup vs baseline: 22.7405x; 1.9915x over previous
//
#include <hip/hip_runtime.h>
#include <cstdint>
#include <cstddef>

#define TPB 256

static inline int cdiv(long long a, int b){ return (int)((a + (long long)b - 1) / b); }

// ---------------- CSR build ----------------

__global__ void k_degs(const int* __restrict__ ei, int* __restrict__ rowdeg,
                       int* __restrict__ dstdeg, int E){
  int e = blockIdx.x*blockDim.x + threadIdx.x;
  if (e >= E) return;
  atomicAdd(&rowdeg[ei[e]], 1);
  atomicAdd(&dstdeg[ei[E + e]], 1);
}

__global__ void k_dis(const int* __restrict__ rowdeg, float* __restrict__ dis, int N){
  int n = blockIdx.x*blockDim.x + threadIdx.x;
  if (n >= N) return;
  int d = rowdeg[n];
  dis[n] = d > 0 ? rsqrtf((float)d) : 0.f;
}

__global__ void k_scan(const int* __restrict__ cnt, int* __restrict__ rp,
                       int* __restrict__ cursor, int N){
  __shared__ int part[257];
  int tid = threadIdx.x;
  int chunk = (N + 255) / 256;
  int lo = tid*chunk; if (lo > N) lo = N;
  int hi = lo + chunk; if (hi > N) hi = N;
  int s = 0;
  for (int i = lo; i < hi; ++i) s += cnt[i];
  part[tid+1] = s;
  if (tid == 0) part[0] = 0;
  __syncthreads();
  if (tid == 0){ for (int i = 1; i <= 256; ++i) part[i] += part[i-1]; }
  __syncthreads();
  int run = part[tid];
  for (int i = lo; i < hi; ++i){ rp[i] = run; cursor[i] = run; run += cnt[i]; }
  if (tid == 0) rp[N] = part[256];
}

__global__ void k_fill(const int* __restrict__ ei, const float* __restrict__ dis,
                       int* __restrict__ cursor, int* __restrict__ srcs,
                       float* __restrict__ wcsr, int E){
  int e = blockIdx.x*blockDim.x + threadIdx.x;
  if (e >= E) return;
  int src = ei[e], dst = ei[E + e];
  int pos = atomicAdd(&cursor[dst], 1);
  srcs[pos] = src;
  wcsr[pos] = dis[src] * dis[dst];
}

// ---------------- row helpers ----------------

template<int F>
__device__ __forceinline__ void loadrow(const float* __restrict__ p, float* r){
  if constexpr (F % 4 == 0){
    #pragma unroll
    for (int q = 0; q < F/4; ++q){
      float4 v = *reinterpret_cast<const float4*>(p + 4*q);
      r[4*q] = v.x; r[4*q+1] = v.y; r[4*q+2] = v.z; r[4*q+3] = v.w;
    }
  } else {
    #pragma unroll
    for (int f = 0; f < F; ++f) r[f] = p[f];
  }
}

template<int F>
__device__ __forceinline__ void storerow(float* __restrict__ p, const float* r){
  if constexpr (F % 4 == 0){
    #pragma unroll
    for (int q = 0; q < F/4; ++q){
      float4 v; v.x = r[4*q]; v.y = r[4*q+1]; v.z = r[4*q+2]; v.w = r[4*q+3];
      *reinterpret_cast<float4*>(p + 4*q) = v;
    }
  } else {
    #pragma unroll
    for (int f = 0; f < F; ++f) p[f] = r[f];
  }
}

// ---------------- fused Chebyshev kernels ----------------

// first: covers k=0 and k=1. T1 = prop(X); out = bias + X@W0 + T1@W1
template<int Fin, int Fout>
__global__ void k_cheb_first(const int* __restrict__ rp, const int* __restrict__ srcs,
                             const float* __restrict__ w,
                             const float* __restrict__ X, float* __restrict__ T1,
                             float* __restrict__ out,
                             const float* __restrict__ W6, const float* __restrict__ bias,
                             int G, int N){
  int i = blockIdx.x*blockDim.x + threadIdx.x;
  if (i >= G*N) return;
  int n = i % N;
  const float* xb = X + (size_t)(i - n)*Fin;   // g*N*Fin
  float t0r[Fin], t1r[Fin];
  loadrow<Fin>(X + (size_t)i*Fin, t0r);
  #pragma unroll
  for (int f = 0; f < Fin; ++f) t1r[f] = 0.f;
  int j0 = rp[n], j1 = rp[n+1];
  for (int j = j0; j < j1; ++j){
    float ww = w[j];
    const float* sr = xb + (size_t)srcs[j]*Fin;
    if constexpr (Fin % 4 == 0){
      #pragma unroll
      for (int q = 0; q < Fin/4; ++q){
        float4 v = *reinterpret_cast<const float4*>(sr + 4*q);
        t1r[4*q]   = fmaf(ww, v.x, t1r[4*q]);
        t1r[4*q+1] = fmaf(ww, v.y, t1r[4*q+1]);
        t1r[4*q+2] = fmaf(ww, v.z, t1r[4*q+2]);
        t1r[4*q+3] = fmaf(ww, v.w, t1r[4*q+3]);
      }
    } else {
      #pragma unroll
      for (int f = 0; f < Fin; ++f) t1r[f] = fmaf(ww, sr[f], t1r[f]);
    }
  }
  storerow<Fin>(T1 + (size_t)i*Fin, t1r);
  float o[Fout];
  #pragma unroll
  for (int fo = 0; fo < Fout; ++fo) o[fo] = bias ? bias[fo] : 0.f;
  #pragma unroll
  for (int fi = 0; fi < Fin; ++fi){
    #pragma unroll
    for (int fo = 0; fo < Fout; ++fo){
      o[fo] = fmaf(t0r[fi], W6[fi*Fout + fo], o[fo]);
      o[fo] = fmaf(t1r[fi], W6[(Fin + fi)*Fout + fo], o[fo]);
    }
  }
  storerow<Fout>(out + (size_t)i*Fout, o);
}

// step k>=2: Tk = 2*prop(Tm1) - Tm2; out += Tk@Wk; optional relu (last step)
template<int Fin, int Fout>
__global__ void k_cheb_step(const int* __restrict__ rp, const int* __restrict__ srcs,
                            const float* __restrict__ w,
                            const float* __restrict__ Tm1, const float* __restrict__ Tm2,
                            float* __restrict__ Tk, float* __restrict__ out,
                            const float* __restrict__ Wk,
                            int G, int N, int relu){
  int i = blockIdx.x*blockDim.x + threadIdx.x;
  if (i >= G*N) return;
  int n = i % N;
  const float* xb = Tm1 + (size_t)(i - n)*Fin;
  float tr[Fin];
  #pragma unroll
  for (int f = 0; f < Fin; ++f) tr[f] = 0.f;
  int j0 = rp[n], j1 = rp[n+1];
  for (int j = j0; j < j1; ++j){
    float ww = w[j];
    const float* sr = xb + (size_t)srcs[j]*Fin;
    if constexpr (Fin % 4 == 0){
      #pragma unroll
      for (int q = 0; q < Fin/4; ++q){
        float4 v = *reinterpret_cast<const float4*>(sr + 4*q);
        tr[4*q]   = fmaf(ww, v.x, tr[4*q]);
        tr[4*q+1] = fmaf(ww, v.y, tr[4*q+1]);
        tr[4*q+2] = fmaf(ww, v.z, tr[4*q+2]);
        tr[4*q+3] = fmaf(ww, v.w, tr[4*q+3]);
      }
    } else {
      #pragma unroll
      for (int f = 0; f < Fin; ++f) tr[f] = fmaf(ww, sr[f], tr[f]);
    }
  }
  float t2r[Fin];
  loadrow<Fin>(Tm2 + (size_t)i*Fin, t2r);
  #pragma unroll
  for (int f = 0; f < Fin; ++f) tr[f] = 2.f*tr[f] - t2r[f];
  storerow<Fin>(Tk + (size_t)i*Fin, tr);
  float o[Fout];
  loadrow<Fout>(out + (size_t)i*Fout, o);
  #pragma unroll
  for (int fi = 0; fi < Fin; ++fi){
    #pragma unroll
    for (int fo = 0; fo < Fout; ++fo)
      o[fo] = fmaf(tr[fi], Wk[fi*Fout + fo], o[fo]);
  }
  if (relu){
    #pragma unroll
    for (int fo = 0; fo < Fout; ++fo) o[fo] = fmaxf(o[fo], 0.f);
  }
  storerow<Fout>(out + (size_t)i*Fout, o);
}

// ---------------- other model kernels ----------------

__global__ void k_phase_enc(const float* __restrict__ x, float* __restrict__ h, int N){
  int i = blockIdx.x*blockDim.x + threadIdx.x;
  if (i >= 32*N) return;
  int n = i % N, g = i / N;
  int t = g & 15;
  float th = 6.283185307179586f * (float)t / 16.0f;
  float s, c;
  sincosf(th, &s, &c);
  const float* xr = x + ((size_t)g*N + n)*3;
  float* hr = h + ((size_t)g*N + n)*6;
  float a0 = xr[0], a1 = xr[1], a2 = xr[2];
  hr[0] = a0*c; hr[1] = a1*c; hr[2] = a2*c;
  hr[3] = a0*s; hr[4] = a1*s; hr[5] = a2*s;
}

template<int F>
__global__ void k_pool_t(const float* __restrict__ X, const int* __restrict__ idx,
                         const float* __restrict__ w, float* __restrict__ out,
                         int G, int Nin, int Nout){
  int i = blockIdx.x*blockDim.x + threadIdx.x;
  if (i >= G*Nout) return;
  int n = i % Nout, g = i / Nout;
  int i0 = idx[n*3+0], i1 = idx[n*3+1], i2 = idx[n*3+2];
  float w0 = w[n*3+0], w1 = w[n*3+1], w2 = w[n*3+2];
  const float* b = X + (size_t)g*Nin*F;
  float r0[F], r1[F], r2[F], o[F];
  loadrow<F>(b + (size_t)i0*F, r0);
  loadrow<F>(b + (size_t)i1*F, r1);
  loadrow<F>(b + (size_t)i2*F, r2);
  #pragma unroll
  for (int f = 0; f < F; ++f)
    o[f] = fmaf(w0, r0[f], fmaf(w1, r1[f], w2 * r2[f]));
  storerow<F>(out + ((size_t)g*Nout + n)*F, o);
}

// mu: one wave per (g,z), coalesced + shuffle reduce
__global__ void k_mu(const float* __restrict__ h, const float* __restrict__ W,
                     const float* __restrict__ b, float* __restrict__ mu){
  int wid = (blockIdx.x*blockDim.x + threadIdx.x) >> 6;
  int lane = threadIdx.x & 63;
  if (wid >= 32*48) return;
  int z = wid % 48, g = wid / 48;
  const float* hr = h + (size_t)g*2048;
  const float* wr = W + (size_t)z*2048;
  float acc = 0.f;
  for (int f = lane; f < 2048; f += 64) acc = fmaf(hr[f], wr[f], acc);
  for (int o = 32; o > 0; o >>= 1) acc += __shfl_down(acc, o, 64);
  if (lane == 0) mu[wid] = acc + b[z];
}

__global__ void k_mucs(const float* __restrict__ mu, float* __restrict__ muc,
                       float* __restrict__ mus, float* __restrict__ out){
  int i = blockIdx.x*blockDim.x + threadIdx.x;
  if (i >= 96) return;
  int z = i % 48, bp = i / 48;
  float acc = 0.f;
  for (int b = 0; b < 2; ++b)
    for (int t = 8*bp; t < 8*bp + 8; ++t)
      acc += mu[(b*16 + t)*48 + z];
  acc *= (1.f/16.f);
  if (z < 32){ muc[bp*32 + z] = acc; out[bp*32 + z] = acc; }
  else       { mus[bp*16 + (z-32)] = acc; out[64 + bp*16 + (z-32)] = acc; }
}

__global__ void k_zin(const float* __restrict__ muc, const float* __restrict__ mus,
                      float* __restrict__ zin){
  int i = blockIdx.x*blockDim.x + threadIdx.x;
  if (i >= 32*64) return;
  int c = i % 64, g = i / 64;
  int b = g / 16, t = g % 16;
  float v;
  if (c < 32){
    v = muc[b*32 + c];
  } else {
    float th = 6.283185307179586f * (float)t / 16.0f;
    int k = c - 32;
    int kk = (k < 16) ? k : (k - 16);
    float m = mus[b*16 + kk];
    v = (k < 16) ? m * cosf(th) : m * sinf(th);
  }
  zin[i] = v;
}

__global__ void k_lin(const float* __restrict__ z, const float* __restrict__ W,
                      const float* __restrict__ b, float* __restrict__ y,
                      int G, int Z, int relu){
  int i = blockIdx.x*blockDim.x + threadIdx.x;
  if (i >= G*2048) return;
  int f = i % 2048, g = i / 2048;
  const float* zr = z + (size_t)g*Z;
  const float* wr = W + (size_t)f*Z;
  float acc = b[f];
  for (int k = 0; k < Z; ++k) acc = fmaf(zr[k], wr[k], acc);
  if (relu) acc = fmaxf(acc, 0.f);
  y[i] = acc;
}

__global__ void k_st(const float* __restrict__ savg, const float* __restrict__ ds,
                     float* __restrict__ st, int N){
  int i = blockIdx.x*blockDim.x + threadIdx.x;
  if (i >= 32*N*3) return;
  int c = i % (N*3);
  int g = i / (N*3);
  int b = g >> 4;
  st[i] = savg[(size_t)b*N*3 + c] + ds[i];
}

// ---------------- host orchestration ----------------

struct Csr { const int* rp; const int* srcs; const float* w; };

static void launch_first(hipStream_t s, int Fin, int Fout, const Csr& A,
                         const float* X, float* T1, float* out,
                         const float* W6, const float* bias, int G, int N){
  long long GN = (long long)G*N;
  dim3 gr(cdiv(GN,TPB)), bl(TPB);
  if      (Fin==6  && Fout==16) k_cheb_first<6,16><<<gr,bl,0,s>>>(A.rp,A.srcs,A.w,X,T1,out,W6,bias,G,N);
  else if (Fin==16 && Fout==16) k_cheb_first<16,16><<<gr,bl,0,s>>>(A.rp,A.srcs,A.w,X,T1,out,W6,bias,G,N);
  else if (Fin==16 && Fout==32) k_cheb_first<16,32><<<gr,bl,0,s>>>(A.rp,A.srcs,A.w,X,T1,out,W6,bias,G,N);
  else if (Fin==32 && Fout==16) k_cheb_first<32,16><<<gr,bl,0,s>>>(A.rp,A.srcs,A.w,X,T1,out,W6,bias,G,N);
  else if (Fin==16 && Fout==3 ) k_cheb_first<16,3 ><<<gr,bl,0,s>>>(A.rp,A.srcs,A.w,X,T1,out,W6,bias,G,N);
}

static void launch_step(hipStream_t s, int Fin, int Fout, const Csr& A,
                        const float* Tm1, const float* Tm2, float* Tk, float* out,
                        const float* Wk, int G, int N, int relu){
  long long GN = (long long)G*N;
  dim3 gr(cdiv(GN,TPB)), bl(TPB);
  if      (Fin==6  && Fout==16) k_cheb_step<6,16><<<gr,bl,0,s>>>(A.rp,A.srcs,A.w,Tm1,Tm2,Tk,out,Wk,G,N,relu);
  else if (Fin==16 && Fout==16) k_cheb_step<16,16><<<gr,bl,0,s>>>(A.rp,A.srcs,A.w,Tm1,Tm2,Tk,out,Wk,G,N,relu);
  else if (Fin==16 && Fout==32) k_cheb_step<16,32><<<gr,bl,0,s>>>(A.rp,A.srcs,A.w,Tm1,Tm2,Tk,out,Wk,G,N,relu);
  else if (Fin==32 && Fout==16) k_cheb_step<32,16><<<gr,bl,0,s>>>(A.rp,A.srcs,A.w,Tm1,Tm2,Tk,out,Wk,G,N,relu);
  else if (Fin==16 && Fout==3 ) k_cheb_step<16,3 ><<<gr,bl,0,s>>>(A.rp,A.srcs,A.w,Tm1,Tm2,Tk,out,Wk,G,N,relu);
}

static void launch_pool(hipStream_t s, int F, const float* X, const int* idx,
                        const float* w, float* out, int G, int Nin, int Nout){
  long long GNo = (long long)G*Nout;
  dim3 gr(cdiv(GNo,TPB)), bl(TPB);
  if (F == 16) k_pool_t<16><<<gr,bl,0,s>>>(X, idx, w, out, G, Nin, Nout);
  else         k_pool_t<32><<<gr,bl,0,s>>>(X, idx, w, out, G, Nin, Nout);
}

// Chebyshev conv, K=6. Trashes X, T1, S. out distinct from X/T1/S.
static void run_cheb(hipStream_t s, const Csr& A, int N, int G,
                     float* X, float* T1, float* S, float* out,
                     const float* W6, const float* bias, int Fin, int Fout, bool relu){
  launch_first(s, Fin, Fout, A, X, T1, out, W6, bias, G, N);
  float* t0 = X; float* t1 = T1; float* sp = S;
  for (int k = 2; k < 6; ++k){
    int last = (k == 5 && relu) ? 1 : 0;
    launch_step(s, Fin, Fout, A, t1, t0, sp, out, W6 + (size_t)k*Fin*Fout, G, N, last);
    float* tmp = t0; t0 = t1; t1 = sp; sp = tmp;
  }
}

static void run_dec(hipStream_t s, int G, const float* z, int Z,
                    const float* lW, const float* lb, bool relu_first,
                    const float* const* W, const float* const* Bc,
                    const Csr* A, const int* const* us_i, const float* const* us_w,
                    float* B0, float* B1, float* B2, float* B3, float* out_final){
  k_lin<<<cdiv((long long)G*2048,TPB),TPB,0,s>>>(z, lW, lb, B0, G, Z, relu_first ? 1 : 0);
  launch_pool(s, 32, B0, us_i[3], us_w[3], B1, G, 64, 256);
  run_cheb(s, A[3], 256, G, B1, B0, B2, B3, W[0], Bc[0], 32, 16, true);
  launch_pool(s, 16, B3, us_i[2], us_w[2], B0, G, 256, 1024);
  run_cheb(s, A[2], 1024, G, B0, B1, B2, B3, W[1], Bc[1], 16, 16, true);
  launch_pool(s, 16, B3, us_i[1], us_w[1], B0, G, 1024, 4096);
  run_cheb(s, A[1], 4096, G, B0, B1, B2, B3, W[2], Bc[2], 16, 16, true);
  launch_pool(s, 16, B3, us_i[0], us_w[0], B0, G, 4096, 16384);
  run_cheb(s, A[4], 16384, G, B0, B1, B2, out_final, W[3], nullptr, 16, 3, false);
}

extern "C" void kernel_launch(void* const* d_in, const int* in_sizes, int n_in,
                              void* d_out, int out_size, void* d_ws, size_t ws_size,
                              hipStream_t stream){
  const float* x = (const float*)d_in[0];
  const float* encW[4] = {(const float*)d_in[1],(const float*)d_in[3],(const float*)d_in[5],(const float*)d_in[7]};
  const float* encB[4] = {(const float*)d_in[2],(const float*)d_in[4],(const float*)d_in[6],(const float*)d_in[8]};
  const float* ccW[4]  = {(const float*)d_in[9],(const float*)d_in[11],(const float*)d_in[13],(const float*)d_in[15]};
  const float* ccB[3]  = {(const float*)d_in[10],(const float*)d_in[12],(const float*)d_in[14]};
  const float* csW[4]  = {(const float*)d_in[16],(const float*)d_in[18],(const float*)d_in[20],(const float*)d_in[22]};
  const float* csB[3]  = {(const float*)d_in[17],(const float*)d_in[19],(const float*)d_in[21]};
  const float* muW  = (const float*)d_in[23]; const float* muB  = (const float*)d_in[24];
  const float* lincW = (const float*)d_in[25]; const float* lincB = (const float*)d_in[26];
  const float* linsW = (const float*)d_in[27]; const float* linsB = (const float*)d_in[28];
  const int* ei[5] = {(const int*)d_in[29],(const int*)d_in[30],(const int*)d_in[31],
                      (const int*)d_in[32],(const int*)d_in[33]};
  const int* ds_i[4]; const float* ds_w[4]; const int* us_i[4]; const float* us_w[4];
  for (int l = 0; l < 4; ++l){
    ds_i[l] = (const int*)d_in[34 + 4*l]; ds_w[l] = (const float*)d_in[35 + 4*l];
    us_i[l] = (const int*)d_in[36 + 4*l]; us_w[l] = (const float*)d_in[37 + 4*l];
  }

  float* ws = (float*)d_ws;
  const size_t BIG = 8388608;   // 32*16384*16 floats
  float* B0 = ws + 0*BIG;
  float* B1 = ws + 1*BIG;
  float* B2 = ws + 2*BIG;
  float* B3 = ws + 3*BIG;
  size_t off = 4*BIG;

  int Es[5] = {196608, 49152, 12288, 3072, 196608};
  int Nn[5] = {16384, 4096, 1024, 256, 16384};

  int* rp[5]; int* cursor[5]; int* srcs[5]; float* wcsr[5];
  for (int l = 0; l < 5; ++l){
    rp[l]     = (int*)(ws + off); off += (size_t)Nn[l] + 1;
    cursor[l] = (int*)(ws + off); off += (size_t)Nn[l] + 1;
    srcs[l]   = (int*)(ws + off); off += (size_t)Es[l];
    wcsr[l]   =        ws + off;  off += (size_t)Es[l];
  }
  int* rowdeg = (int*)(ws + off); off += 16384;
  int* dstdeg = (int*)(ws + off); off += 16384;
  float* dis  = ws + off; off += 16384;
  float* hmu = ws + off; off += (size_t)32*2048;
  float* mu  = ws + off; off += (size_t)32*48;
  float* muc = ws + off; off += 64;
  float* mus = ws + off; off += 32;
  float* zin = ws + off; off += (size_t)32*64;

  float* outp = (float*)d_out;
  float* out_savg = outp + 96;         // [2,16384,3]
  float* out_st   = outp + 96 + 98304; // [2,16,16384,3]

  // ---- CSR build per level ----
  for (int l = 0; l < 5; ++l){
    hipMemsetAsync(rowdeg, 0, (size_t)Nn[l]*sizeof(int), stream);
    hipMemsetAsync(dstdeg, 0, (size_t)Nn[l]*sizeof(int), stream);
    k_degs<<<cdiv(Es[l],TPB),TPB,0,stream>>>(ei[l], rowdeg, dstdeg, Es[l]);
    k_dis<<<cdiv(Nn[l],TPB),TPB,0,stream>>>(rowdeg, dis, Nn[l]);
    k_scan<<<1,256,0,stream>>>(dstdeg, rp[l], cursor[l], Nn[l]);
    k_fill<<<cdiv(Es[l],TPB),TPB,0,stream>>>(ei[l], dis, cursor[l], srcs[l], wcsr[l], Es[l]);
  }
  Csr A[5];
  for (int l = 0; l < 5; ++l) A[l] = Csr{rp[l], srcs[l], wcsr[l]};

  // ---- encoder ----
  k_phase_enc<<<cdiv((long long)32*16384,TPB),TPB,0,stream>>>(x, B0, 16384);
  int NSl[5] = {16384, 4096, 1024, 256, 64};
  int Fi[4] = {6,16,16,16}, Fo[4] = {16,16,16,32};
  for (int l = 0; l < 4; ++l){
    run_cheb(stream, A[l], NSl[l], 32, B0, B1, B2, B3, encW[l], encB[l], Fi[l], Fo[l], true);
    float* dst = (l == 3) ? hmu : B0;
    launch_pool(stream, Fo[l], B3, ds_i[l], ds_w[l], dst, 32, NSl[l], NSl[l+1]);
  }

  // ---- latent ----
  k_mu<<<cdiv((long long)32*48*64,TPB),TPB,0,stream>>>(hmu, muW, muB, mu);
  k_mucs<<<1,128,0,stream>>>(mu, muc, mus, outp);

  // ---- decoder c (G=2) -> s_avg in d_out ----
  run_dec(stream, 2, muc, 32, lincW, lincB, false, ccW, ccB,
          A, us_i, us_w, B0, B1, B2, B3, out_savg);

  // ---- decoder s (G=32) -> ds_t in B3 ----
  k_zin<<<cdiv(32*64,TPB),TPB,0,stream>>>(muc, mus, zin);
  run_dec(stream, 32, zin, 64, linsW, linsB, true, csW, csB,
          A, us_i, us_w, B0, B1, B2, B3, B3);

  // ---- s_t = s_avg + ds_t ----
  k_st<<<cdiv((long long)32*16384*3,TPB),TPB,0,stream>>>(out_savg, B3, out_st, 16384);

  (void)in_sizes; (void)n_in; (void)out_size; (void)ws_size;
}

// Round 6
// 2197.822 us; speedup vs baseline: 25.3725x; 1.1157x over previous
//
#include <hip/hip_runtime.h>
#include <cstdint>
#include <cstddef>

#define TPB 256

typedef float f32x4 __attribute__((ext_vector_type(4)));

static inline int cdiv(long long a, int b){ return (int)((a + (long long)b - 1) / b); }

// ---------------- CSR build ----------------

__global__ void k_degs(const int* __restrict__ ei, int* __restrict__ rowdeg,
                       int* __restrict__ dstdeg, int E){
  int e = blockIdx.x*blockDim.x + threadIdx.x;
  if (e >= E) return;
  atomicAdd(&rowdeg[ei[e]], 1);
  atomicAdd(&dstdeg[ei[E + e]], 1);
}

__global__ void k_dis(const int* __restrict__ rowdeg, float* __restrict__ dis, int N){
  int n = blockIdx.x*blockDim.x + threadIdx.x;
  if (n >= N) return;
  int d = rowdeg[n];
  dis[n] = d > 0 ? rsqrtf((float)d) : 0.f;
}

__global__ void k_scan(const int* __restrict__ cnt, int* __restrict__ rp,
                       int* __restrict__ cursor, int N){
  __shared__ int part[257];
  int tid = threadIdx.x;
  int chunk = (N + 255) / 256;
  int lo = tid*chunk; if (lo > N) lo = N;
  int hi = lo + chunk; if (hi > N) hi = N;
  int s = 0;
  for (int i = lo; i < hi; ++i) s += cnt[i];
  part[tid+1] = s;
  if (tid == 0) part[0] = 0;
  __syncthreads();
  if (tid == 0){ for (int i = 1; i <= 256; ++i) part[i] += part[i-1]; }
  __syncthreads();
  int run = part[tid];
  for (int i = lo; i < hi; ++i){ rp[i] = run; cursor[i] = run; run += cnt[i]; }
  if (tid == 0) rp[N] = part[256];
}

__global__ void k_fill(const int* __restrict__ ei, const float* __restrict__ dis,
                       int* __restrict__ cursor, int* __restrict__ srcs,
                       float* __restrict__ wcsr, int E){
  int e = blockIdx.x*blockDim.x + threadIdx.x;
  if (e >= E) return;
  int src = ei[e], dst = ei[E + e];
  int pos = atomicAdd(&cursor[dst], 1);
  srcs[pos] = src;
  wcsr[pos] = dis[src] * dis[dst];
}

// ---------------- row helpers ----------------

template<int F>
__device__ __forceinline__ void loadrow(const float* __restrict__ p, float* r){
  if constexpr (F % 4 == 0){
    #pragma unroll
    for (int q = 0; q < F/4; ++q){
      f32x4 v = *reinterpret_cast<const f32x4*>(p + 4*q);
      r[4*q] = v.x; r[4*q+1] = v.y; r[4*q+2] = v.z; r[4*q+3] = v.w;
    }
  } else {
    #pragma unroll
    for (int f = 0; f < F; ++f) r[f] = p[f];
  }
}

template<int F>
__device__ __forceinline__ void storerow(float* __restrict__ p, const float* r){
  if constexpr (F % 4 == 0){
    #pragma unroll
    for (int q = 0; q < F/4; ++q){
      f32x4 v; v.x = r[4*q]; v.y = r[4*q+1]; v.z = r[4*q+2]; v.w = r[4*q+3];
      *reinterpret_cast<f32x4*>(p + 4*q) = v;
    }
  } else {
    #pragma unroll
    for (int f = 0; f < F; ++f) p[f] = r[f];
  }
}

// non-temporal (streaming) variants: don't pollute L2 gather working set
template<int F>
__device__ __forceinline__ void loadrow_nt(const float* __restrict__ p, float* r){
  if constexpr (F % 4 == 0){
    #pragma unroll
    for (int q = 0; q < F/4; ++q){
      f32x4 v = __builtin_nontemporal_load(reinterpret_cast<const f32x4*>(p) + q);
      r[4*q] = v.x; r[4*q+1] = v.y; r[4*q+2] = v.z; r[4*q+3] = v.w;
    }
  } else {
    #pragma unroll
    for (int f = 0; f < F; ++f) r[f] = __builtin_nontemporal_load(p + f);
  }
}

template<int F>
__device__ __forceinline__ void storerow_nt(float* __restrict__ p, const float* r){
  if constexpr (F % 4 == 0){
    #pragma unroll
    for (int q = 0; q < F/4; ++q){
      f32x4 v; v.x = r[4*q]; v.y = r[4*q+1]; v.z = r[4*q+2]; v.w = r[4*q+3];
      __builtin_nontemporal_store(v, reinterpret_cast<f32x4*>(p) + q);
    }
  } else {
    #pragma unroll
    for (int f = 0; f < F; ++f) __builtin_nontemporal_store(r[f], p + f);
  }
}

// XCD-aware block swizzle: for G==32 grids (nb%32==0), pin g-slice to XCD
// (blockIdx%8 -> XCD round-robin). g = (j/bpg)*8 + (bid&7): each XCD owns
// 4 g-slices -> gather working set ~4MB fits its private L2.
__device__ __forceinline__ long long swz_i(int G){
  int bid = blockIdx.x, nb = gridDim.x;
  if (G == 32 && (nb & 31) == 0){
    int bpg = nb >> 5;
    int xcd = bid & 7, j = bid >> 3;
    int gi = j / bpg, nc = j - gi*bpg;
    bid = ((gi << 3) | xcd) * bpg + nc;
  }
  return (long long)bid * blockDim.x + threadIdx.x;
}

// ---------------- fused Chebyshev kernels ----------------

// first: covers k=0 and k=1. T1 = prop(X); out = bias + X@W0 + T1@W1
template<int Fin, int Fout>
__global__ void k_cheb_first(const int* __restrict__ rp, const int* __restrict__ srcs,
                             const float* __restrict__ w,
                             const float* __restrict__ X, float* __restrict__ T1,
                             float* __restrict__ out,
                             const float* __restrict__ W6, const float* __restrict__ bias,
                             int G, int N){
  long long i = swz_i(G);
  if (i >= (long long)G*N) return;
  int n = (int)(i % N);
  const float* xb = X + (size_t)(i - n)*Fin;   // g*N*Fin
  float t0r[Fin], t1r[Fin];
  loadrow<Fin>(X + (size_t)i*Fin, t0r);
  #pragma unroll
  for (int f = 0; f < Fin; ++f) t1r[f] = 0.f;
  int j0 = rp[n], j1 = rp[n+1];
  for (int j = j0; j < j1; ++j){
    float ww = w[j];
    const float* sr = xb + (size_t)srcs[j]*Fin;
    if constexpr (Fin % 4 == 0){
      #pragma unroll
      for (int q = 0; q < Fin/4; ++q){
        f32x4 v = *reinterpret_cast<const f32x4*>(sr + 4*q);
        t1r[4*q]   = fmaf(ww, v.x, t1r[4*q]);
        t1r[4*q+1] = fmaf(ww, v.y, t1r[4*q+1]);
        t1r[4*q+2] = fmaf(ww, v.z, t1r[4*q+2]);
        t1r[4*q+3] = fmaf(ww, v.w, t1r[4*q+3]);
      }
    } else {
      #pragma unroll
      for (int f = 0; f < Fin; ++f) t1r[f] = fmaf(ww, sr[f], t1r[f]);
    }
  }
  storerow<Fin>(T1 + (size_t)i*Fin, t1r);
  float o[Fout];
  #pragma unroll
  for (int fo = 0; fo < Fout; ++fo) o[fo] = bias ? bias[fo] : 0.f;
  #pragma unroll
  for (int fi = 0; fi < Fin; ++fi){
    #pragma unroll
    for (int fo = 0; fo < Fout; ++fo){
      o[fo] = fmaf(t0r[fi], W6[fi*Fout + fo], o[fo]);
      o[fo] = fmaf(t1r[fi], W6[(Fin + fi)*Fout + fo], o[fo]);
    }
  }
  storerow_nt<Fout>(out + (size_t)i*Fout, o);
}

// step k>=2: Tk = 2*prop(Tm1) - Tm2; out += Tk@Wk; optional relu (last step)
template<int Fin, int Fout>
__global__ void k_cheb_step(const int* __restrict__ rp, const int* __restrict__ srcs,
                            const float* __restrict__ w,
                            const float* __restrict__ Tm1, const float* __restrict__ Tm2,
                            float* __restrict__ Tk, float* __restrict__ out,
                            const float* __restrict__ Wk,
                            int G, int N, int relu){
  long long i = swz_i(G);
  if (i >= (long long)G*N) return;
  int n = (int)(i % N);
  const float* xb = Tm1 + (size_t)(i - n)*Fin;
  float tr[Fin];
  #pragma unroll
  for (int f = 0; f < Fin; ++f) tr[f] = 0.f;
  int j0 = rp[n], j1 = rp[n+1];
  for (int j = j0; j < j1; ++j){
    float ww = w[j];
    const float* sr = xb + (size_t)srcs[j]*Fin;
    if constexpr (Fin % 4 == 0){
      #pragma unroll
      for (int q = 0; q < Fin/4; ++q){
        f32x4 v = *reinterpret_cast<const f32x4*>(sr + 4*q);
        tr[4*q]   = fmaf(ww, v.x, tr[4*q]);
        tr[4*q+1] = fmaf(ww, v.y, tr[4*q+1]);
        tr[4*q+2] = fmaf(ww, v.z, tr[4*q+2]);
        tr[4*q+3] = fmaf(ww, v.w, tr[4*q+3]);
      }
    } else {
      #pragma unroll
      for (int f = 0; f < Fin; ++f) tr[f] = fmaf(ww, sr[f], tr[f]);
    }
  }
  float t2r[Fin];
  loadrow_nt<Fin>(Tm2 + (size_t)i*Fin, t2r);
  #pragma unroll
  for (int f = 0; f < Fin; ++f) tr[f] = 2.f*tr[f] - t2r[f];
  storerow<Fin>(Tk + (size_t)i*Fin, tr);
  float o[Fout];
  loadrow_nt<Fout>(out + (size_t)i*Fout, o);
  #pragma unroll
  for (int fi = 0; fi < Fin; ++fi){
    #pragma unroll
    for (int fo = 0; fo < Fout; ++fo)
      o[fo] = fmaf(tr[fi], Wk[fi*Fout + fo], o[fo]);
  }
  if (relu){
    #pragma unroll
    for (int fo = 0; fo < Fout; ++fo) o[fo] = fmaxf(o[fo], 0.f);
  }
  storerow_nt<Fout>(out + (size_t)i*Fout, o);
}

// ---------------- other model kernels ----------------

__global__ void k_phase_enc(const float* __restrict__ x, float* __restrict__ h, int N){
  int i = blockIdx.x*blockDim.x + threadIdx.x;
  if (i >= 32*N) return;
  int n = i % N, g = i / N;
  int t = g & 15;
  float th = 6.283185307179586f * (float)t / 16.0f;
  float s, c;
  sincosf(th, &s, &c);
  const float* xr = x + ((size_t)g*N + n)*3;
  float* hr = h + ((size_t)g*N + n)*6;
  float a0 = xr[0], a1 = xr[1], a2 = xr[2];
  hr[0] = a0*c; hr[1] = a1*c; hr[2] = a2*c;
  hr[3] = a0*s; hr[4] = a1*s; hr[5] = a2*s;
}

template<int F>
__global__ void k_pool_t(const float* __restrict__ X, const int* __restrict__ idx,
                         const float* __restrict__ w, float* __restrict__ out,
                         int G, int Nin, int Nout){
  long long i = swz_i(G);
  if (i >= (long long)G*Nout) return;
  int n = (int)(i % Nout), g = (int)(i / Nout);
  int i0 = idx[n*3+0], i1 = idx[n*3+1], i2 = idx[n*3+2];
  float w0 = w[n*3+0], w1 = w[n*3+1], w2 = w[n*3+2];
  const float* b = X + (size_t)g*Nin*F;
  float r0[F], r1[F], r2[F], o[F];
  loadrow<F>(b + (size_t)i0*F, r0);
  loadrow<F>(b + (size_t)i1*F, r1);
  loadrow<F>(b + (size_t)i2*F, r2);
  #pragma unroll
  for (int f = 0; f < F; ++f)
    o[f] = fmaf(w0, r0[f], fmaf(w1, r1[f], w2 * r2[f]));
  storerow<F>(out + ((size_t)g*Nout + n)*F, o);
}

// mu: one wave per (g,z), coalesced + shuffle reduce
__global__ void k_mu(const float* __restrict__ h, const float* __restrict__ W,
                     const float* __restrict__ b, float* __restrict__ mu){
  int wid = (blockIdx.x*blockDim.x + threadIdx.x) >> 6;
  int lane = threadIdx.x & 63;
  if (wid >= 32*48) return;
  int z = wid % 48, g = wid / 48;
  const float* hr = h + (size_t)g*2048;
  const float* wr = W + (size_t)z*2048;
  float acc = 0.f;
  for (int f = lane; f < 2048; f += 64) acc = fmaf(hr[f], wr[f], acc);
  for (int o = 32; o > 0; o >>= 1) acc += __shfl_down(acc, o, 64);
  if (lane == 0) mu[wid] = acc + b[z];
}

__global__ void k_mucs(const float* __restrict__ mu, float* __restrict__ muc,
                       float* __restrict__ mus, float* __restrict__ out){
  int i = blockIdx.x*blockDim.x + threadIdx.x;
  if (i >= 96) return;
  int z = i % 48, bp = i / 48;
  float acc = 0.f;
  for (int b = 0; b < 2; ++b)
    for (int t = 8*bp; t < 8*bp + 8; ++t)
      acc += mu[(b*16 + t)*48 + z];
  acc *= (1.f/16.f);
  if (z < 32){ muc[bp*32 + z] = acc; out[bp*32 + z] = acc; }
  else       { mus[bp*16 + (z-32)] = acc; out[64 + bp*16 + (z-32)] = acc; }
}

__global__ void k_zin(const float* __restrict__ muc, const float* __restrict__ mus,
                      float* __restrict__ zin){
  int i = blockIdx.x*blockDim.x + threadIdx.x;
  if (i >= 32*64) return;
  int c = i % 64, g = i / 64;
  int b = g / 16, t = g % 16;
  float v;
  if (c < 32){
    v = muc[b*32 + c];
  } else {
    float th = 6.283185307179586f * (float)t / 16.0f;
    int k = c - 32;
    int kk = (k < 16) ? k : (k - 16);
    float m = mus[b*16 + kk];
    v = (k < 16) ? m * cosf(th) : m * sinf(th);
  }
  zin[i] = v;
}

__global__ void k_lin(const float* __restrict__ z, const float* __restrict__ W,
                      const float* __restrict__ b, float* __restrict__ y,
                      int G, int Z, int relu){
  int i = blockIdx.x*blockDim.x + threadIdx.x;
  if (i >= G*2048) return;
  int f = i % 2048, g = i / 2048;
  const float* zr = z + (size_t)g*Z;
  const float* wr = W + (size_t)f*Z;
  float acc = b[f];
  for (int k = 0; k < Z; ++k) acc = fmaf(zr[k], wr[k], acc);
  if (relu) acc = fmaxf(acc, 0.f);
  y[i] = acc;
}

__global__ void k_st(const float* __restrict__ savg, const float* __restrict__ ds,
                     float* __restrict__ st, int N){
  int i = blockIdx.x*blockDim.x + threadIdx.x;
  if (i >= 32*N*3) return;
  int c = i % (N*3);
  int g = i / (N*3);
  int b = g >> 4;
  st[i] = savg[(size_t)b*N*3 + c] + ds[i];
}

// ---------------- host orchestration ----------------

struct Csr { const int* rp; const int* srcs; const float* w; };

static void launch_first(hipStream_t s, int Fin, int Fout, const Csr& A,
                         const float* X, float* T1, float* out,
                         const float* W6, const float* bias, int G, int N){
  long long GN = (long long)G*N;
  dim3 gr(cdiv(GN,TPB)), bl(TPB);
  if      (Fin==6  && Fout==16) k_cheb_first<6,16><<<gr,bl,0,s>>>(A.rp,A.srcs,A.w,X,T1,out,W6,bias,G,N);
  else if (Fin==16 && Fout==16) k_cheb_first<16,16><<<gr,bl,0,s>>>(A.rp,A.srcs,A.w,X,T1,out,W6,bias,G,N);
  else if (Fin==16 && Fout==32) k_cheb_first<16,32><<<gr,bl,0,s>>>(A.rp,A.srcs,A.w,X,T1,out,W6,bias,G,N);
  else if (Fin==32 && Fout==16) k_cheb_first<32,16><<<gr,bl,0,s>>>(A.rp,A.srcs,A.w,X,T1,out,W6,bias,G,N);
  else if (Fin==16 && Fout==3 ) k_cheb_first<16,3 ><<<gr,bl,0,s>>>(A.rp,A.srcs,A.w,X,T1,out,W6,bias,G,N);
}

static void launch_step(hipStream_t s, int Fin, int Fout, const Csr& A,
                        const float* Tm1, const float* Tm2, float* Tk, float* out,
                        const float* Wk, int G, int N, int relu){
  long long GN = (long long)G*N;
  dim3 gr(cdiv(GN,TPB)), bl(TPB);
  if      (Fin==6  && Fout==16) k_cheb_step<6,16><<<gr,bl,0,s>>>(A.rp,A.srcs,A.w,Tm1,Tm2,Tk,out,Wk,G,N,relu);
  else if (Fin==16 && Fout==16) k_cheb_step<16,16><<<gr,bl,0,s>>>(A.rp,A.srcs,A.w,Tm1,Tm2,Tk,out,Wk,G,N,relu);
  else if (Fin==16 && Fout==32) k_cheb_step<16,32><<<gr,bl,0,s>>>(A.rp,A.srcs,A.w,Tm1,Tm2,Tk,out,Wk,G,N,relu);
  else if (Fin==32 && Fout==16) k_cheb_step<32,16><<<gr,bl,0,s>>>(A.rp,A.srcs,A.w,Tm1,Tm2,Tk,out,Wk,G,N,relu);
  else if (Fin==16 && Fout==3 ) k_cheb_step<16,3 ><<<gr,bl,0,s>>>(A.rp,A.srcs,A.w,Tm1,Tm2,Tk,out,Wk,G,N,relu);
}

static void launch_pool(hipStream_t s, int F, const float* X, const int* idx,
                        const float* w, float* out, int G, int Nin, int Nout){
  long long GNo = (long long)G*Nout;
  dim3 gr(cdiv(GNo,TPB)), bl(TPB);
  if (F == 16) k_pool_t<16><<<gr,bl,0,s>>>(X, idx, w, out, G, Nin, Nout);
  else         k_pool_t<32><<<gr,bl,0,s>>>(X, idx, w, out, G, Nin, Nout);
}

// Chebyshev conv, K=6. Trashes X, T1, S. out distinct from X/T1/S.
static void run_cheb(hipStream_t s, const Csr& A, int N, int G,
                     float* X, float* T1, float* S, float* out,
                     const float* W6, const float* bias, int Fin, int Fout, bool relu){
  launch_first(s, Fin, Fout, A, X, T1, out, W6, bias, G, N);
  float* t0 = X; float* t1 = T1; float* sp = S;
  for (int k = 2; k < 6; ++k){
    int last = (k == 5 && relu) ? 1 : 0;
    launch_step(s, Fin, Fout, A, t1, t0, sp, out, W6 + (size_t)k*Fin*Fout, G, N, last);
    float* tmp = t0; t0 = t1; t1 = sp; sp = tmp;
  }
}

static void run_dec(hipStream_t s, int G, const float* z, int Z,
                    const float* lW, const float* lb, bool relu_first,
                    const float* const* W, const float* const* Bc,
                    const Csr* A, const int* const* us_i, const float* const* us_w,
                    float* B0, float* B1, float* B2, float* B3, float* out_final){
  k_lin<<<cdiv((long long)G*2048,TPB),TPB,0,s>>>(z, lW, lb, B0, G, Z, relu_first ? 1 : 0);
  launch_pool(s, 32, B0, us_i[3], us_w[3], B1, G, 64, 256);
  run_cheb(s, A[3], 256, G, B1, B0, B2, B3, W[0], Bc[0], 32, 16, true);
  launch_pool(s, 16, B3, us_i[2], us_w[2], B0, G, 256, 1024);
  run_cheb(s, A[2], 1024, G, B0, B1, B2, B3, W[1], Bc[1], 16, 16, true);
  launch_pool(s, 16, B3, us_i[1], us_w[1], B0, G, 1024, 4096);
  run_cheb(s, A[1], 4096, G, B0, B1, B2, B3, W[2], Bc[2], 16, 16, true);
  launch_pool(s, 16, B3, us_i[0], us_w[0], B0, G, 4096, 16384);
  run_cheb(s, A[4], 16384, G, B0, B1, B2, out_final, W[3], nullptr, 16, 3, false);
}

extern "C" void kernel_launch(void* const* d_in, const int* in_sizes, int n_in,
                              void* d_out, int out_size, void* d_ws, size_t ws_size,
                              hipStream_t stream){
  const float* x = (const float*)d_in[0];
  const float* encW[4] = {(const float*)d_in[1],(const float*)d_in[3],(const float*)d_in[5],(const float*)d_in[7]};
  const float* encB[4] = {(const float*)d_in[2],(const float*)d_in[4],(const float*)d_in[6],(const float*)d_in[8]};
  const float* ccW[4]  = {(const float*)d_in[9],(const float*)d_in[11],(const float*)d_in[13],(const float*)d_in[15]};
  const float* ccB[3]  = {(const float*)d_in[10],(const float*)d_in[12],(const float*)d_in[14]};
  const float* csW[4]  = {(const float*)d_in[16],(const float*)d_in[18],(const float*)d_in[20],(const float*)d_in[22]};
  const float* csB[3]  = {(const float*)d_in[17],(const float*)d_in[19],(const float*)d_in[21]};
  const float* muW  = (const float*)d_in[23]; const float* muB  = (const float*)d_in[24];
  const float* lincW = (const float*)d_in[25]; const float* lincB = (const float*)d_in[26];
  const float* linsW = (const float*)d_in[27]; const float* linsB = (const float*)d_in[28];
  const int* ei[5] = {(const int*)d_in[29],(const int*)d_in[30],(const int*)d_in[31],
                      (const int*)d_in[32],(const int*)d_in[33]};
  const int* ds_i[4]; const float* ds_w[4]; const int* us_i[4]; const float* us_w[4];
  for (int l = 0; l < 4; ++l){
    ds_i[l] = (const int*)d_in[34 + 4*l]; ds_w[l] = (const float*)d_in[35 + 4*l];
    us_i[l] = (const int*)d_in[36 + 4*l]; us_w[l] = (const float*)d_in[37 + 4*l];
  }

  float* ws = (float*)d_ws;
  const size_t BIG = 8388608;   // 32*16384*16 floats
  float* B0 = ws + 0*BIG;
  float* B1 = ws + 1*BIG;
  float* B2 = ws + 2*BIG;
  float* B3 = ws + 3*BIG;
  size_t off = 4*BIG;

  int Es[5] = {196608, 49152, 12288, 3072, 196608};
  int Nn[5] = {16384, 4096, 1024, 256, 16384};

  int* rp[5]; int* cursor[5]; int* srcs[5]; float* wcsr[5];
  for (int l = 0; l < 5; ++l){
    rp[l]     = (int*)(ws + off); off += (size_t)Nn[l] + 1;
    cursor[l] = (int*)(ws + off); off += (size_t)Nn[l] + 1;
    srcs[l]   = (int*)(ws + off); off += (size_t)Es[l];
    wcsr[l]   =        ws + off;  off += (size_t)Es[l];
  }
  int* rowdeg = (int*)(ws + off); off += 16384;
  int* dstdeg = (int*)(ws + off); off += 16384;
  float* dis  = ws + off; off += 16384;
  float* hmu = ws + off; off += (size_t)32*2048;
  float* mu  = ws + off; off += (size_t)32*48;
  float* muc = ws + off; off += 64;
  float* mus = ws + off; off += 32;
  float* zin = ws + off; off += (size_t)32*64;

  float* outp = (float*)d_out;
  float* out_savg = outp + 96;         // [2,16384,3]
  float* out_st   = outp + 96 + 98304; // [2,16,16384,3]

  // ---- CSR build per level ----
  for (int l = 0; l < 5; ++l){
    hipMemsetAsync(rowdeg, 0, (size_t)Nn[l]*sizeof(int), stream);
    hipMemsetAsync(dstdeg, 0, (size_t)Nn[l]*sizeof(int), stream);
    k_degs<<<cdiv(Es[l],TPB),TPB,0,stream>>>(ei[l], rowdeg, dstdeg, Es[l]);
    k_dis<<<cdiv(Nn[l],TPB),TPB,0,stream>>>(rowdeg, dis, Nn[l]);
    k_scan<<<1,256,0,stream>>>(dstdeg, rp[l], cursor[l], Nn[l]);
    k_fill<<<cdiv(Es[l],TPB),TPB,0,stream>>>(ei[l], dis, cursor[l], srcs[l], wcsr[l], Es[l]);
  }
  Csr A[5];
  for (int l = 0; l < 5; ++l) A[l] = Csr{rp[l], srcs[l], wcsr[l]};

  // ---- encoder ----
  k_phase_enc<<<cdiv((long long)32*16384,TPB),TPB,0,stream>>>(x, B0, 16384);
  int NSl[5] = {16384, 4096, 1024, 256, 64};
  int Fi[4] = {6,16,16,16}, Fo[4] = {16,16,16,32};
  for (int l = 0; l < 4; ++l){
    run_cheb(stream, A[l], NSl[l], 32, B0, B1, B2, B3, encW[l], encB[l], Fi[l], Fo[l], true);
    float* dst = (l == 3) ? hmu : B0;
    launch_pool(stream, Fo[l], B3, ds_i[l], ds_w[l], dst, 32, NSl[l], NSl[l+1]);
  }

  // ---- latent ----
  k_mu<<<cdiv((long long)32*48*64,TPB),TPB,0,stream>>>(hmu, muW, muB, mu);
  k_mucs<<<1,128,0,stream>>>(mu, muc, mus, outp);

  // ---- decoder c (G=2) -> s_avg in d_out ----
  run_dec(stream, 2, muc, 32, lincW, lincB, false, ccW, ccB,
          A, us_i, us_w, B0, B1, B2, B3, out_savg);

  // ---- decoder s (G=32) -> ds_t in B3 ----
  k_zin<<<cdiv(32*64,TPB),TPB,0,stream>>>(muc, mus, zin);
  run_dec(stream, 32, zin, 64, linsW, linsB, true, csW, csB,
          A, us_i, us_w, B0, B1, B2, B3, B3);

  // ---- s_t = s_avg + ds_t ----
  k_st<<<cdiv((long long)32*16384*3,TPB),TPB,0,stream>>>(out_savg, B3, out_st, 16384);

  (void)in_sizes; (void)n_in; (void)out_size; (void)ws_size;
}

// Round 7
// 2105.644 us; speedup vs baseline: 26.4832x; 1.0438x over previous
//
#include <hip/hip_runtime.h>
#include <cstdint>
#include <cstddef>

#define TPB 256

typedef float f32x4 __attribute__((ext_vector_type(4)));
typedef float f32x2 __attribute__((ext_vector_type(2)));

static inline int cdiv(long long a, int b){ return (int)((a + (long long)b - 1) / b); }

// ---------------- CSR build ----------------

__global__ void k_degs(const int* __restrict__ ei, int* __restrict__ rowdeg,
                       int* __restrict__ dstdeg, int E){
  int e = blockIdx.x*blockDim.x + threadIdx.x;
  if (e >= E) return;
  atomicAdd(&rowdeg[ei[e]], 1);
  atomicAdd(&dstdeg[ei[E + e]], 1);
}

__global__ void k_dis(const int* __restrict__ rowdeg, float* __restrict__ dis, int N){
  int n = blockIdx.x*blockDim.x + threadIdx.x;
  if (n >= N) return;
  int d = rowdeg[n];
  dis[n] = d > 0 ? rsqrtf((float)d) : 0.f;
}

__global__ void k_scan(const int* __restrict__ cnt, int* __restrict__ rp,
                       int* __restrict__ cursor, int N){
  __shared__ int part[257];
  int tid = threadIdx.x;
  int chunk = (N + 255) / 256;
  int lo = tid*chunk; if (lo > N) lo = N;
  int hi = lo + chunk; if (hi > N) hi = N;
  int s = 0;
  for (int i = lo; i < hi; ++i) s += cnt[i];
  part[tid+1] = s;
  if (tid == 0) part[0] = 0;
  __syncthreads();
  if (tid == 0){ for (int i = 1; i <= 256; ++i) part[i] += part[i-1]; }
  __syncthreads();
  int run = part[tid];
  for (int i = lo; i < hi; ++i){ rp[i] = run; cursor[i] = run; run += cnt[i]; }
  if (tid == 0) rp[N] = part[256];
}

__global__ void k_fill(const int* __restrict__ ei, const float* __restrict__ dis,
                       int* __restrict__ cursor, int* __restrict__ srcs,
                       float* __restrict__ wcsr, int E){
  int e = blockIdx.x*blockDim.x + threadIdx.x;
  if (e >= E) return;
  int src = ei[e], dst = ei[E + e];
  int pos = atomicAdd(&cursor[dst], 1);
  srcs[pos] = src;
  wcsr[pos] = dis[src] * dis[dst];
}

// ---------------- small vector helpers ----------------

template<int W>
__device__ __forceinline__ void vload(const float* __restrict__ p, float* r){
  if constexpr (W == 4){ f32x4 v = *reinterpret_cast<const f32x4*>(p); r[0]=v.x;r[1]=v.y;r[2]=v.z;r[3]=v.w; }
  else                 { f32x2 v = *reinterpret_cast<const f32x2*>(p); r[0]=v.x;r[1]=v.y; }
}
template<int W>
__device__ __forceinline__ void vstore(float* __restrict__ p, const float* r){
  if constexpr (W == 4){ f32x4 v; v.x=r[0];v.y=r[1];v.z=r[2];v.w=r[3]; *reinterpret_cast<f32x4*>(p) = v; }
  else                 { f32x2 v; v.x=r[0];v.y=r[1]; *reinterpret_cast<f32x2*>(p) = v; }
}
template<int W>
__device__ __forceinline__ void vload_nt(const float* __restrict__ p, float* r){
  if constexpr (W == 4){ f32x4 v = __builtin_nontemporal_load(reinterpret_cast<const f32x4*>(p)); r[0]=v.x;r[1]=v.y;r[2]=v.z;r[3]=v.w; }
  else                 { f32x2 v = __builtin_nontemporal_load(reinterpret_cast<const f32x2*>(p)); r[0]=v.x;r[1]=v.y; }
}
template<int W>
__device__ __forceinline__ void vstore_nt(float* __restrict__ p, const float* r){
  if constexpr (W == 4){ f32x4 v; v.x=r[0];v.y=r[1];v.z=r[2];v.w=r[3]; __builtin_nontemporal_store(v, reinterpret_cast<f32x4*>(p)); }
  else                 { f32x2 v; v.x=r[0];v.y=r[1]; __builtin_nontemporal_store(v, reinterpret_cast<f32x2*>(p)); }
}

template<int F>
__device__ __forceinline__ void loadrow(const float* __restrict__ p, float* r){
  if constexpr (F % 4 == 0){
    #pragma unroll
    for (int q = 0; q < F/4; ++q){ float v[4]; vload<4>(p + 4*q, v); r[4*q]=v[0];r[4*q+1]=v[1];r[4*q+2]=v[2];r[4*q+3]=v[3]; }
  } else {
    #pragma unroll
    for (int f = 0; f < F; ++f) r[f] = p[f];
  }
}
template<int F>
__device__ __forceinline__ void storerow(float* __restrict__ p, const float* r){
  if constexpr (F % 4 == 0){
    #pragma unroll
    for (int q = 0; q < F/4; ++q) vstore<4>(p + 4*q, r + 4*q);
  } else {
    #pragma unroll
    for (int f = 0; f < F; ++f) p[f] = r[f];
  }
}
template<int F>
__device__ __forceinline__ void loadrow_nt(const float* __restrict__ p, float* r){
  #pragma unroll
  for (int q = 0; q < F/4; ++q) vload_nt<4>(p + 4*q, r + 4*q);
}
template<int F>
__device__ __forceinline__ void storerow_nt(float* __restrict__ p, const float* r){
  #pragma unroll
  for (int q = 0; q < F/4; ++q) vstore_nt<4>(p + 4*q, r + 4*q);
}

// XCD-aware block swizzle: for G==32 grids (nb%32==0), pin g-slice to XCD
__device__ __forceinline__ long long swz_i(int G){
  int bid = blockIdx.x, nb = gridDim.x;
  if (G == 32 && (nb & 31) == 0){
    int bpg = nb >> 5;
    int xcd = bid & 7, j = bid >> 3;
    int gi = j / bpg, nc = j - gi*bpg;
    bid = ((gi << 3) | xcd) * bpg + nc;
  }
  return (long long)bid * blockDim.x + threadIdx.x;
}

// ---------------- 4-lane-per-row fused Chebyshev kernels ----------------
// Lanes 4k..4k+3 share one (g,n) row; each lane owns FPL=FinPad/4 floats.

template<int FinPad, int FinReal, int Fout>
__global__ void k_cheb4_first(const int* __restrict__ rp, const int* __restrict__ srcs,
                              const float* __restrict__ w,
                              const float* __restrict__ X, float* __restrict__ T1,
                              float* __restrict__ out,
                              const float* __restrict__ W6, const float* __restrict__ bias,
                              int G, int N){
  constexpr int FPL = FinPad/4;
  long long i4 = swz_i(G);
  if (i4 >= (long long)G*N*4) return;
  int sub = (int)(i4 & 3);
  long long i = i4 >> 2;
  int n = (int)(i % N);
  const float* gb = X + (size_t)(i - n)*FinPad;
  float t0[FPL], t1[FPL];
  vload<FPL>(X + (size_t)i*FinPad + sub*FPL, t0);
  #pragma unroll
  for (int q = 0; q < FPL; ++q) t1[q] = 0.f;
  int j0 = rp[n], j1 = rp[n+1];
  for (int j = j0; j < j1; ++j){
    float ww = w[j];
    float v[FPL];
    vload<FPL>(gb + (size_t)srcs[j]*FinPad + sub*FPL, v);
    #pragma unroll
    for (int q = 0; q < FPL; ++q) t1[q] = fmaf(ww, v[q], t1[q]);
  }
  vstore<FPL>(T1 + (size_t)i*FinPad + sub*FPL, t1);
  // assemble full rows across the 4-lane group
  float t0v[FinPad], t1v[FinPad];
  int base = (int)(threadIdx.x & 63) & ~3;
  #pragma unroll
  for (int s = 0; s < 4; ++s){
    #pragma unroll
    for (int q = 0; q < FPL; ++q){
      t0v[s*FPL+q] = __shfl(t0[q], base + s, 64);
      t1v[s*FPL+q] = __shfl(t1[q], base + s, 64);
    }
  }
  if constexpr (Fout % 4 == 0){
    constexpr int OPL = Fout/4;
    float o[OPL];
    #pragma unroll
    for (int q = 0; q < OPL; ++q) o[q] = bias ? bias[sub*OPL + q] : 0.f;
    #pragma unroll
    for (int fi = 0; fi < FinReal; ++fi){
      #pragma unroll
      for (int q = 0; q < OPL; ++q){
        o[q] = fmaf(t0v[fi], W6[fi*Fout + sub*OPL + q], o[q]);
        o[q] = fmaf(t1v[fi], W6[(FinReal + fi)*Fout + sub*OPL + q], o[q]);
      }
    }
    vstore_nt<OPL>(out + (size_t)i*Fout + sub*OPL, o);
  } else {
    if (sub < Fout){
      float acc = bias ? bias[sub] : 0.f;
      #pragma unroll
      for (int fi = 0; fi < FinReal; ++fi){
        acc = fmaf(t0v[fi], W6[fi*Fout + sub], acc);
        acc = fmaf(t1v[fi], W6[(FinReal + fi)*Fout + sub], acc);
      }
      __builtin_nontemporal_store(acc, out + (size_t)i*Fout + sub);
    }
  }
}

template<int FinPad, int FinReal, int Fout>
__global__ void k_cheb4_step(const int* __restrict__ rp, const int* __restrict__ srcs,
                             const float* __restrict__ w,
                             const float* __restrict__ Tm1, const float* __restrict__ Tm2,
                             float* __restrict__ Tk, float* __restrict__ out,
                             const float* __restrict__ Wk,
                             int G, int N, int relu){
  constexpr int FPL = FinPad/4;
  long long i4 = swz_i(G);
  if (i4 >= (long long)G*N*4) return;
  int sub = (int)(i4 & 3);
  long long i = i4 >> 2;
  int n = (int)(i % N);
  const float* gb = Tm1 + (size_t)(i - n)*FinPad;
  float tr[FPL];
  #pragma unroll
  for (int q = 0; q < FPL; ++q) tr[q] = 0.f;
  int j0 = rp[n], j1 = rp[n+1];
  for (int j = j0; j < j1; ++j){
    float ww = w[j];
    float v[FPL];
    vload<FPL>(gb + (size_t)srcs[j]*FinPad + sub*FPL, v);
    #pragma unroll
    for (int q = 0; q < FPL; ++q) tr[q] = fmaf(ww, v[q], tr[q]);
  }
  float t2[FPL];
  vload_nt<FPL>(Tm2 + (size_t)i*FinPad + sub*FPL, t2);
  #pragma unroll
  for (int q = 0; q < FPL; ++q) tr[q] = 2.f*tr[q] - t2[q];
  vstore<FPL>(Tk + (size_t)i*FinPad + sub*FPL, tr);
  float trv[FinPad];
  int base = (int)(threadIdx.x & 63) & ~3;
  #pragma unroll
  for (int s = 0; s < 4; ++s){
    #pragma unroll
    for (int q = 0; q < FPL; ++q)
      trv[s*FPL+q] = __shfl(tr[q], base + s, 64);
  }
  if constexpr (Fout % 4 == 0){
    constexpr int OPL = Fout/4;
    float o[OPL];
    vload_nt<OPL>(out + (size_t)i*Fout + sub*OPL, o);
    #pragma unroll
    for (int fi = 0; fi < FinReal; ++fi){
      #pragma unroll
      for (int q = 0; q < OPL; ++q)
        o[q] = fmaf(trv[fi], Wk[fi*Fout + sub*OPL + q], o[q]);
    }
    if (relu){
      #pragma unroll
      for (int q = 0; q < OPL; ++q) o[q] = fmaxf(o[q], 0.f);
    }
    vstore_nt<OPL>(out + (size_t)i*Fout + sub*OPL, o);
  } else {
    if (sub < Fout){
      float acc = __builtin_nontemporal_load(out + (size_t)i*Fout + sub);
      #pragma unroll
      for (int fi = 0; fi < FinReal; ++fi)
        acc = fmaf(trv[fi], Wk[fi*Fout + sub], acc);
      if (relu) acc = fmaxf(acc, 0.f);
      __builtin_nontemporal_store(acc, out + (size_t)i*Fout + sub);
    }
  }
}

// ---------------- old lane-per-row Cheb kernels (small levels only) ----------------

template<int Fin, int Fout>
__global__ void k_cheb_first(const int* __restrict__ rp, const int* __restrict__ srcs,
                             const float* __restrict__ w,
                             const float* __restrict__ X, float* __restrict__ T1,
                             float* __restrict__ out,
                             const float* __restrict__ W6, const float* __restrict__ bias,
                             int G, int N){
  long long i = swz_i(G);
  if (i >= (long long)G*N) return;
  int n = (int)(i % N);
  const float* xb = X + (size_t)(i - n)*Fin;
  float t0r[Fin], t1r[Fin];
  loadrow<Fin>(X + (size_t)i*Fin, t0r);
  #pragma unroll
  for (int f = 0; f < Fin; ++f) t1r[f] = 0.f;
  int j0 = rp[n], j1 = rp[n+1];
  for (int j = j0; j < j1; ++j){
    float ww = w[j];
    const float* sr = xb + (size_t)srcs[j]*Fin;
    #pragma unroll
    for (int f = 0; f < Fin; ++f) t1r[f] = fmaf(ww, sr[f], t1r[f]);
  }
  storerow<Fin>(T1 + (size_t)i*Fin, t1r);
  float o[Fout];
  #pragma unroll
  for (int fo = 0; fo < Fout; ++fo) o[fo] = bias ? bias[fo] : 0.f;
  #pragma unroll
  for (int fi = 0; fi < Fin; ++fi){
    #pragma unroll
    for (int fo = 0; fo < Fout; ++fo){
      o[fo] = fmaf(t0r[fi], W6[fi*Fout + fo], o[fo]);
      o[fo] = fmaf(t1r[fi], W6[(Fin + fi)*Fout + fo], o[fo]);
    }
  }
  storerow<Fout>(out + (size_t)i*Fout, o);
}

template<int Fin, int Fout>
__global__ void k_cheb_step(const int* __restrict__ rp, const int* __restrict__ srcs,
                            const float* __restrict__ w,
                            const float* __restrict__ Tm1, const float* __restrict__ Tm2,
                            float* __restrict__ Tk, float* __restrict__ out,
                            const float* __restrict__ Wk,
                            int G, int N, int relu){
  long long i = swz_i(G);
  if (i >= (long long)G*N) return;
  int n = (int)(i % N);
  const float* xb = Tm1 + (size_t)(i - n)*Fin;
  float tr[Fin];
  #pragma unroll
  for (int f = 0; f < Fin; ++f) tr[f] = 0.f;
  int j0 = rp[n], j1 = rp[n+1];
  for (int j = j0; j < j1; ++j){
    float ww = w[j];
    const float* sr = xb + (size_t)srcs[j]*Fin;
    #pragma unroll
    for (int f = 0; f < Fin; ++f) tr[f] = fmaf(ww, sr[f], tr[f]);
  }
  float t2r[Fin];
  loadrow<Fin>(Tm2 + (size_t)i*Fin, t2r);
  #pragma unroll
  for (int f = 0; f < Fin; ++f) tr[f] = 2.f*tr[f] - t2r[f];
  storerow<Fin>(Tk + (size_t)i*Fin, tr);
  float o[Fout];
  loadrow<Fout>(out + (size_t)i*Fout, o);
  #pragma unroll
  for (int fi = 0; fi < Fin; ++fi){
    #pragma unroll
    for (int fo = 0; fo < Fout; ++fo)
      o[fo] = fmaf(tr[fi], Wk[fi*Fout + fo], o[fo]);
  }
  if (relu){
    #pragma unroll
    for (int fo = 0; fo < Fout; ++fo) o[fo] = fmaxf(o[fo], 0.f);
  }
  storerow<Fout>(out + (size_t)i*Fout, o);
}

// ---------------- other model kernels ----------------

// x: [2,16,N,3] -> h8: [32,N,8] padded (last 2 = 0)
__global__ void k_phase_enc8(const float* __restrict__ x, float* __restrict__ h, int N){
  int i = blockIdx.x*blockDim.x + threadIdx.x;
  if (i >= 32*N) return;
  int n = i % N, g = i / N;
  int t = g & 15;
  float th = 6.283185307179586f * (float)t / 16.0f;
  float s, c;
  sincosf(th, &s, &c);
  const float* xr = x + ((size_t)g*N + n)*3;
  float a0 = xr[0], a1 = xr[1], a2 = xr[2];
  float hr[8] = {a0*c, a1*c, a2*c, a0*s, a1*s, a2*s, 0.f, 0.f};
  storerow<8>(h + ((size_t)g*N + n)*8, hr);
}

template<int F>
__global__ void k_pool_t(const float* __restrict__ X, const int* __restrict__ idx,
                         const float* __restrict__ w, float* __restrict__ out,
                         int G, int Nin, int Nout){
  long long i = swz_i(G);
  if (i >= (long long)G*Nout) return;
  int n = (int)(i % Nout), g = (int)(i / Nout);
  int i0 = idx[n*3+0], i1 = idx[n*3+1], i2 = idx[n*3+2];
  float w0 = w[n*3+0], w1 = w[n*3+1], w2 = w[n*3+2];
  const float* b = X + (size_t)g*Nin*F;
  float r0[F], r1[F], r2[F], o[F];
  loadrow<F>(b + (size_t)i0*F, r0);
  loadrow<F>(b + (size_t)i1*F, r1);
  loadrow<F>(b + (size_t)i2*F, r2);
  #pragma unroll
  for (int f = 0; f < F; ++f)
    o[f] = fmaf(w0, r0[f], fmaf(w1, r1[f], w2 * r2[f]));
  storerow<F>(out + ((size_t)g*Nout + n)*F, o);
}

// mu: one wave per (g,z), coalesced + shuffle reduce
__global__ void k_mu(const float* __restrict__ h, const float* __restrict__ W,
                     const float* __restrict__ b, float* __restrict__ mu){
  int wid = (blockIdx.x*blockDim.x + threadIdx.x) >> 6;
  int lane = threadIdx.x & 63;
  if (wid >= 32*48) return;
  int z = wid % 48, g = wid / 48;
  const float* hr = h + (size_t)g*2048;
  const float* wr = W + (size_t)z*2048;
  float acc = 0.f;
  for (int f = lane; f < 2048; f += 64) acc = fmaf(hr[f], wr[f], acc);
  for (int o = 32; o > 0; o >>= 1) acc += __shfl_down(acc, o, 64);
  if (lane == 0) mu[wid] = acc + b[z];
}

__global__ void k_mucs(const float* __restrict__ mu, float* __restrict__ muc,
                       float* __restrict__ mus, float* __restrict__ out){
  int i = blockIdx.x*blockDim.x + threadIdx.x;
  if (i >= 96) return;
  int z = i % 48, bp = i / 48;
  float acc = 0.f;
  for (int b = 0; b < 2; ++b)
    for (int t = 8*bp; t < 8*bp + 8; ++t)
      acc += mu[(b*16 + t)*48 + z];
  acc *= (1.f/16.f);
  if (z < 32){ muc[bp*32 + z] = acc; out[bp*32 + z] = acc; }
  else       { mus[bp*16 + (z-32)] = acc; out[64 + bp*16 + (z-32)] = acc; }
}

__global__ void k_zin(const float* __restrict__ muc, const float* __restrict__ mus,
                      float* __restrict__ zin){
  int i = blockIdx.x*blockDim.x + threadIdx.x;
  if (i >= 32*64) return;
  int c = i % 64, g = i / 64;
  int b = g / 16, t = g % 16;
  float v;
  if (c < 32){
    v = muc[b*32 + c];
  } else {
    float th = 6.283185307179586f * (float)t / 16.0f;
    int k = c - 32;
    int kk = (k < 16) ? k : (k - 16);
    float m = mus[b*16 + kk];
    v = (k < 16) ? m * cosf(th) : m * sinf(th);
  }
  zin[i] = v;
}

__global__ void k_lin(const float* __restrict__ z, const float* __restrict__ W,
                      const float* __restrict__ b, float* __restrict__ y,
                      int G, int Z, int relu){
  int i = blockIdx.x*blockDim.x + threadIdx.x;
  if (i >= G*2048) return;
  int f = i % 2048, g = i / 2048;
  const float* zr = z + (size_t)g*Z;
  const float* wr = W + (size_t)f*Z;
  float acc = b[f];
  for (int k = 0; k < Z; ++k) acc = fmaf(zr[k], wr[k], acc);
  if (relu) acc = fmaxf(acc, 0.f);
  y[i] = acc;
}

__global__ void k_st(const float* __restrict__ savg, const float* __restrict__ ds,
                     float* __restrict__ st, int N){
  int i = blockIdx.x*blockDim.x + threadIdx.x;
  if (i >= 32*N*3) return;
  int c = i % (N*3);
  int g = i / (N*3);
  int b = g >> 4;
  st[i] = savg[(size_t)b*N*3 + c] + ds[i];
}

// ---------------- host orchestration ----------------

struct Csr { const int* rp; const int* srcs; const float* w; };

// ---- 4-lane path (FinPad/FinReal/Fout in {(8,6,16),(16,16,16),(16,16,3)}) ----
static void launch4_first(hipStream_t s, int FinPad, int Fout, const Csr& A,
                          const float* X, float* T1, float* out,
                          const float* W6, const float* bias, int G, int N){
  long long GN4 = (long long)G*N*4;
  dim3 gr(cdiv(GN4,TPB)), bl(TPB);
  if      (FinPad == 8) k_cheb4_first<8,6,16><<<gr,bl,0,s>>>(A.rp,A.srcs,A.w,X,T1,out,W6,bias,G,N);
  else if (Fout == 16)  k_cheb4_first<16,16,16><<<gr,bl,0,s>>>(A.rp,A.srcs,A.w,X,T1,out,W6,bias,G,N);
  else                  k_cheb4_first<16,16,3><<<gr,bl,0,s>>>(A.rp,A.srcs,A.w,X,T1,out,W6,bias,G,N);
}

static void launch4_step(hipStream_t s, int FinPad, int Fout, const Csr& A,
                         const float* Tm1, const float* Tm2, float* Tk, float* out,
                         const float* Wk, int G, int N, int relu){
  long long GN4 = (long long)G*N*4;
  dim3 gr(cdiv(GN4,TPB)), bl(TPB);
  if      (FinPad == 8) k_cheb4_step<8,6,16><<<gr,bl,0,s>>>(A.rp,A.srcs,A.w,Tm1,Tm2,Tk,out,Wk,G,N,relu);
  else if (Fout == 16)  k_cheb4_step<16,16,16><<<gr,bl,0,s>>>(A.rp,A.srcs,A.w,Tm1,Tm2,Tk,out,Wk,G,N,relu);
  else                  k_cheb4_step<16,16,3><<<gr,bl,0,s>>>(A.rp,A.srcs,A.w,Tm1,Tm2,Tk,out,Wk,G,N,relu);
}

// FinReal is the W leading dim (6 for padded level, else 16)
static void run_cheb4(hipStream_t s, const Csr& A, int N, int G,
                      float* X, float* T1, float* S, float* out,
                      const float* W6, const float* bias,
                      int FinPad, int FinReal, int Fout, bool relu){
  launch4_first(s, FinPad, Fout, A, X, T1, out, W6, bias, G, N);
  float* t0 = X; float* t1 = T1; float* sp = S;
  for (int k = 2; k < 6; ++k){
    int last = (k == 5 && relu) ? 1 : 0;
    launch4_step(s, FinPad, Fout, A, t1, t0, sp, out, W6 + (size_t)k*FinReal*Fout, G, N, last);
    float* tmp = t0; t0 = t1; t1 = sp; sp = tmp;
  }
}

// ---- old path (N=256 levels: (16,32) and (32,16)) ----
static void run_cheb_old(hipStream_t s, const Csr& A, int N, int G,
                         float* X, float* T1, float* S, float* out,
                         const float* W6, const float* bias, int Fin, int Fout, bool relu){
  long long GN = (long long)G*N;
  dim3 gr(cdiv(GN,TPB)), bl(TPB);
  if (Fin == 16)
    k_cheb_first<16,32><<<gr,bl,0,s>>>(A.rp,A.srcs,A.w,X,T1,out,W6,bias,G,N);
  else
    k_cheb_first<32,16><<<gr,bl,0,s>>>(A.rp,A.srcs,A.w,X,T1,out,W6,bias,G,N);
  float* t0 = X; float* t1 = T1; float* sp = S;
  for (int k = 2; k < 6; ++k){
    int last = (k == 5 && relu) ? 1 : 0;
    if (Fin == 16)
      k_cheb_step<16,32><<<gr,bl,0,s>>>(A.rp,A.srcs,A.w,t1,t0,sp,out,W6 + (size_t)k*Fin*Fout,G,N,last);
    else
      k_cheb_step<32,16><<<gr,bl,0,s>>>(A.rp,A.srcs,A.w,t1,t0,sp,out,W6 + (size_t)k*Fin*Fout,G,N,last);
    float* tmp = t0; t0 = t1; t1 = sp; sp = tmp;
  }
}

static void launch_pool(hipStream_t s, int F, const float* X, const int* idx,
                        const float* w, float* out, int G, int Nin, int Nout){
  long long GNo = (long long)G*Nout;
  dim3 gr(cdiv(GNo,TPB)), bl(TPB);
  if (F == 16) k_pool_t<16><<<gr,bl,0,s>>>(X, idx, w, out, G, Nin, Nout);
  else         k_pool_t<32><<<gr,bl,0,s>>>(X, idx, w, out, G, Nin, Nout);
}

static void run_dec(hipStream_t s, int G, const float* z, int Z,
                    const float* lW, const float* lb, bool relu_first,
                    const float* const* W, const float* const* Bc,
                    const Csr* A, const int* const* us_i, const float* const* us_w,
                    float* B0, float* B1, float* B2, float* B3, float* out_final){
  k_lin<<<cdiv((long long)G*2048,TPB),TPB,0,s>>>(z, lW, lb, B0, G, Z, relu_first ? 1 : 0);
  launch_pool(s, 32, B0, us_i[3], us_w[3], B1, G, 64, 256);
  run_cheb_old(s, A[3], 256, G, B1, B0, B2, B3, W[0], Bc[0], 32, 16, true);
  launch_pool(s, 16, B3, us_i[2], us_w[2], B0, G, 256, 1024);
  run_cheb4(s, A[2], 1024, G, B0, B1, B2, B3, W[1], Bc[1], 16, 16, 16, true);
  launch_pool(s, 16, B3, us_i[1], us_w[1], B0, G, 1024, 4096);
  run_cheb4(s, A[1], 4096, G, B0, B1, B2, B3, W[2], Bc[2], 16, 16, 16, true);
  launch_pool(s, 16, B3, us_i[0], us_w[0], B0, G, 4096, 16384);
  run_cheb4(s, A[4], 16384, G, B0, B1, B2, out_final, W[3], nullptr, 16, 16, 3, false);
}

extern "C" void kernel_launch(void* const* d_in, const int* in_sizes, int n_in,
                              void* d_out, int out_size, void* d_ws, size_t ws_size,
                              hipStream_t stream){
  const float* x = (const float*)d_in[0];
  const float* encW[4] = {(const float*)d_in[1],(const float*)d_in[3],(const float*)d_in[5],(const float*)d_in[7]};
  const float* encB[4] = {(const float*)d_in[2],(const float*)d_in[4],(const float*)d_in[6],(const float*)d_in[8]};
  const float* ccW[4]  = {(const float*)d_in[9],(const float*)d_in[11],(const float*)d_in[13],(const float*)d_in[15]};
  const float* ccB[3]  = {(const float*)d_in[10],(const float*)d_in[12],(const float*)d_in[14]};
  const float* csW[4]  = {(const float*)d_in[16],(const float*)d_in[18],(const float*)d_in[20],(const float*)d_in[22]};
  const float* csB[3]  = {(const float*)d_in[17],(const float*)d_in[19],(const float*)d_in[21]};
  const float* muW  = (const float*)d_in[23]; const float* muB  = (const float*)d_in[24];
  const float* lincW = (const float*)d_in[25]; const float* lincB = (const float*)d_in[26];
  const float* linsW = (const float*)d_in[27]; const float* linsB = (const float*)d_in[28];
  const int* ei[5] = {(const int*)d_in[29],(const int*)d_in[30],(const int*)d_in[31],
                      (const int*)d_in[32],(const int*)d_in[33]};
  const int* ds_i[4]; const float* ds_w[4]; const int* us_i[4]; const float* us_w[4];
  for (int l = 0; l < 4; ++l){
    ds_i[l] = (const int*)d_in[34 + 4*l]; ds_w[l] = (const float*)d_in[35 + 4*l];
    us_i[l] = (const int*)d_in[36 + 4*l]; us_w[l] = (const float*)d_in[37 + 4*l];
  }

  float* ws = (float*)d_ws;
  const size_t BIG = 8388608;   // 32*16384*16 floats
  float* B0 = ws + 0*BIG;
  float* B1 = ws + 1*BIG;
  float* B2 = ws + 2*BIG;
  float* B3 = ws + 3*BIG;
  size_t off = 4*BIG;

  int Es[5] = {196608, 49152, 12288, 3072, 196608};
  int Nn[5] = {16384, 4096, 1024, 256, 16384};

  int* rp[5]; int* cursor[5]; int* srcs[5]; float* wcsr[5];
  for (int l = 0; l < 5; ++l){
    rp[l]     = (int*)(ws + off); off += (size_t)Nn[l] + 1;
    cursor[l] = (int*)(ws + off); off += (size_t)Nn[l] + 1;
    srcs[l]   = (int*)(ws + off); off += (size_t)Es[l];
    wcsr[l]   =        ws + off;  off += (size_t)Es[l];
  }
  int* rowdeg = (int*)(ws + off); off += 16384;
  int* dstdeg = (int*)(ws + off); off += 16384;
  float* dis  = ws + off; off += 16384;
  float* hmu = ws + off; off += (size_t)32*2048;
  float* mu  = ws + off; off += (size_t)32*48;
  float* muc = ws + off; off += 64;
  float* mus = ws + off; off += 32;
  float* zin = ws + off; off += (size_t)32*64;

  float* outp = (float*)d_out;
  float* out_savg = outp + 96;         // [2,16384,3]
  float* out_st   = outp + 96 + 98304; // [2,16,16384,3]

  // ---- CSR build per level ----
  for (int l = 0; l < 5; ++l){
    hipMemsetAsync(rowdeg, 0, (size_t)Nn[l]*sizeof(int), stream);
    hipMemsetAsync(dstdeg, 0, (size_t)Nn[l]*sizeof(int), stream);
    k_degs<<<cdiv(Es[l],TPB),TPB,0,stream>>>(ei[l], rowdeg, dstdeg, Es[l]);
    k_dis<<<cdiv(Nn[l],TPB),TPB,0,stream>>>(rowdeg, dis, Nn[l]);
    k_scan<<<1,256,0,stream>>>(dstdeg, rp[l], cursor[l], Nn[l]);
    k_fill<<<cdiv(Es[l],TPB),TPB,0,stream>>>(ei[l], dis, cursor[l], srcs[l], wcsr[l], Es[l]);
  }
  Csr A[5];
  for (int l = 0; l < 5; ++l) A[l] = Csr{rp[l], srcs[l], wcsr[l]};

  // ---- encoder ----
  k_phase_enc8<<<cdiv((long long)32*16384,TPB),TPB,0,stream>>>(x, B0, 16384);
  // l0: padded 8 (real 6) -> 16
  run_cheb4(stream, A[0], 16384, 32, B0, B1, B2, B3, encW[0], encB[0], 8, 6, 16, true);
  launch_pool(stream, 16, B3, ds_i[0], ds_w[0], B0, 32, 16384, 4096);
  // l1: 16 -> 16
  run_cheb4(stream, A[1], 4096, 32, B0, B1, B2, B3, encW[1], encB[1], 16, 16, 16, true);
  launch_pool(stream, 16, B3, ds_i[1], ds_w[1], B0, 32, 4096, 1024);
  // l2: 16 -> 16
  run_cheb4(stream, A[2], 1024, 32, B0, B1, B2, B3, encW[2], encB[2], 16, 16, 16, true);
  launch_pool(stream, 16, B3, ds_i[2], ds_w[2], B0, 32, 1024, 256);
  // l3: 16 -> 32 (old path)
  run_cheb_old(stream, A[3], 256, 32, B0, B1, B2, B3, encW[3], encB[3], 16, 32, true);
  launch_pool(stream, 32, B3, ds_i[3], ds_w[3], hmu, 32, 256, 64);

  // ---- latent ----
  k_mu<<<cdiv((long long)32*48*64,TPB),TPB,0,stream>>>(hmu, muW, muB, mu);
  k_mucs<<<1,128,0,stream>>>(mu, muc, mus, outp);

  // ---- decoder c (G=2) -> s_avg in d_out ----
  run_dec(stream, 2, muc, 32, lincW, lincB, false, ccW, ccB,
          A, us_i, us_w, B0, B1, B2, B3, out_savg);

  // ---- decoder s (G=32) -> ds_t in B3 ----
  k_zin<<<cdiv(32*64,TPB),TPB,0,stream>>>(muc, mus, zin);
  run_dec(stream, 32, zin, 64, linsW, linsB, true, csW, csB,
          A, us_i, us_w, B0, B1, B2, B3, B3);

  // ---- s_t = s_avg + ds_t ----
  k_st<<<cdiv((long long)32*16384*3,TPB),TPB,0,stream>>>(out_savg, B3, out_st, 16384);

  (void)in_sizes; (void)n_in; (void)out_size; (void)ws_size;
}

// Round 8
// 1679.929 us; speedup vs baseline: 33.1944x; 1.2534x over previous
//
#include <hip/hip_runtime.h>
#include <cstdint>
#include <cstddef>

#define TPB 256

typedef float f32x4 __attribute__((ext_vector_type(4)));
typedef float f32x2 __attribute__((ext_vector_type(2)));
typedef int   i32x4 __attribute__((ext_vector_type(4)));

static inline int cdiv(long long a, int b){ return (int)((a + (long long)b - 1) / b); }

// ---------------- CSR build (rows padded to multiple of 4) ----------------

__global__ void k_degs(const int* __restrict__ ei, int* __restrict__ rowdeg,
                       int* __restrict__ dstdeg, int E){
  int e = blockIdx.x*blockDim.x + threadIdx.x;
  if (e >= E) return;
  atomicAdd(&rowdeg[ei[e]], 1);
  atomicAdd(&dstdeg[ei[E + e]], 1);
}

__global__ void k_dis(const int* __restrict__ rowdeg, float* __restrict__ dis, int N){
  int n = blockIdx.x*blockDim.x + threadIdx.x;
  if (n >= N) return;
  int d = rowdeg[n];
  dis[n] = d > 0 ? rsqrtf((float)d) : 0.f;
}

// exclusive scan of PADDED counts: row n occupies [rp[n], rp[n]+cnt) valid,
// pads up to rp[n+1] (multiple-of-4 row sizes).
__global__ void k_scan(const int* __restrict__ cnt, int* __restrict__ rp,
                       int* __restrict__ cursor, int N){
  __shared__ int part[257];
  int tid = threadIdx.x;
  int chunk = (N + 255) / 256;
  int lo = tid*chunk; if (lo > N) lo = N;
  int hi = lo + chunk; if (hi > N) hi = N;
  int s = 0;
  for (int i = lo; i < hi; ++i) s += (cnt[i] + 3) & ~3;
  part[tid+1] = s;
  if (tid == 0) part[0] = 0;
  __syncthreads();
  if (tid == 0){ for (int i = 1; i <= 256; ++i) part[i] += part[i-1]; }
  __syncthreads();
  int run = part[tid];
  for (int i = lo; i < hi; ++i){ rp[i] = run; cursor[i] = run; run += (cnt[i] + 3) & ~3; }
  if (tid == 0) rp[N] = part[256];
}

__global__ void k_fill(const int* __restrict__ ei, const float* __restrict__ dis,
                       int* __restrict__ cursor, int* __restrict__ srcs,
                       float* __restrict__ wcsr, int E){
  int e = blockIdx.x*blockDim.x + threadIdx.x;
  if (e >= E) return;
  int src = ei[e], dst = ei[E + e];
  int pos = atomicAdd(&cursor[dst], 1);
  srcs[pos] = src;
  wcsr[pos] = dis[src] * dis[dst];
}

// ---------------- small vector helpers ----------------

template<int W>
__device__ __forceinline__ void vload(const float* __restrict__ p, float* r){
  if constexpr (W == 4){ f32x4 v = *reinterpret_cast<const f32x4*>(p); r[0]=v.x;r[1]=v.y;r[2]=v.z;r[3]=v.w; }
  else                 { f32x2 v = *reinterpret_cast<const f32x2*>(p); r[0]=v.x;r[1]=v.y; }
}
template<int W>
__device__ __forceinline__ void vstore(float* __restrict__ p, const float* r){
  if constexpr (W == 4){ f32x4 v; v.x=r[0];v.y=r[1];v.z=r[2];v.w=r[3]; *reinterpret_cast<f32x4*>(p) = v; }
  else                 { f32x2 v; v.x=r[0];v.y=r[1]; *reinterpret_cast<f32x2*>(p) = v; }
}

template<int F>
__device__ __forceinline__ void loadrow(const float* __restrict__ p, float* r){
  if constexpr (F % 4 == 0){
    #pragma unroll
    for (int q = 0; q < F/4; ++q) vload<4>(p + 4*q, r + 4*q);
  } else {
    #pragma unroll
    for (int f = 0; f < F; ++f) r[f] = p[f];
  }
}
template<int F>
__device__ __forceinline__ void storerow(float* __restrict__ p, const float* r){
  if constexpr (F % 4 == 0){
    #pragma unroll
    for (int q = 0; q < F/4; ++q) vstore<4>(p + 4*q, r + 4*q);
  } else {
    #pragma unroll
    for (int f = 0; f < F; ++f) p[f] = r[f];
  }
}

// XCD-aware block swizzle: for G==32 grids (nb%32==0), pin g-slice to XCD
__device__ __forceinline__ long long swz_i(int G){
  int bid = blockIdx.x, nb = gridDim.x;
  if (G == 32 && (nb & 31) == 0){
    int bpg = nb >> 5;
    int xcd = bid & 7, j = bid >> 3;
    int gi = j / bpg, nc = j - gi*bpg;
    bid = ((gi << 3) | xcd) * bpg + nc;
  }
  return (long long)bid * blockDim.x + threadIdx.x;
}

// ---------------- 4-lane-per-row fused Chebyshev kernels ----------------
// Lanes 4k..4k+3 share one (g,n) row; each lane owns FPL=FinPad/4 floats.
// Edge loop is chunked by 4 (CSR rows padded): 1 int4 + 1 float4 index load,
// then 4 independent gathers -> 4x MLP.

template<int FinPad, int FinReal, int Fout>
__global__ void k_cheb4_first(const int* __restrict__ rp, const int* __restrict__ srcs,
                              const float* __restrict__ w,
                              const float* __restrict__ X, float* __restrict__ T1,
                              float* __restrict__ out,
                              const float* __restrict__ W6, const float* __restrict__ bias,
                              int G, int N){
  constexpr int FPL = FinPad/4;
  long long i4 = swz_i(G);
  if (i4 >= (long long)G*N*4) return;
  int sub = (int)(i4 & 3);
  long long i = i4 >> 2;
  int n = (int)(i % N);
  const float* gb = X + (size_t)(i - n)*FinPad;
  float t0[FPL], t1[FPL];
  vload<FPL>(X + (size_t)i*FinPad + sub*FPL, t0);
  #pragma unroll
  for (int q = 0; q < FPL; ++q) t1[q] = 0.f;
  int j0 = rp[n], j1 = rp[n+1];
  for (int j = j0; j < j1; j += 4){
    i32x4 s4 = *reinterpret_cast<const i32x4*>(srcs + j);
    f32x4 w4 = *reinterpret_cast<const f32x4*>(w + j);
    float v0[FPL], v1[FPL], v2[FPL], v3[FPL];
    vload<FPL>(gb + (size_t)s4.x*FinPad + sub*FPL, v0);
    vload<FPL>(gb + (size_t)s4.y*FinPad + sub*FPL, v1);
    vload<FPL>(gb + (size_t)s4.z*FinPad + sub*FPL, v2);
    vload<FPL>(gb + (size_t)s4.w*FinPad + sub*FPL, v3);
    #pragma unroll
    for (int q = 0; q < FPL; ++q){
      t1[q] = fmaf(w4.x, v0[q], t1[q]);
      t1[q] = fmaf(w4.y, v1[q], t1[q]);
      t1[q] = fmaf(w4.z, v2[q], t1[q]);
      t1[q] = fmaf(w4.w, v3[q], t1[q]);
    }
  }
  vstore<FPL>(T1 + (size_t)i*FinPad + sub*FPL, t1);
  // assemble full rows across the 4-lane group
  float t0v[FinPad], t1v[FinPad];
  int base = (int)(threadIdx.x & 63) & ~3;
  #pragma unroll
  for (int s = 0; s < 4; ++s){
    #pragma unroll
    for (int q = 0; q < FPL; ++q){
      t0v[s*FPL+q] = __shfl(t0[q], base + s, 64);
      t1v[s*FPL+q] = __shfl(t1[q], base + s, 64);
    }
  }
  if constexpr (Fout % 4 == 0){
    constexpr int OPL = Fout/4;
    float o[OPL];
    #pragma unroll
    for (int q = 0; q < OPL; ++q) o[q] = bias ? bias[sub*OPL + q] : 0.f;
    #pragma unroll
    for (int fi = 0; fi < FinReal; ++fi){
      #pragma unroll
      for (int q = 0; q < OPL; ++q){
        o[q] = fmaf(t0v[fi], W6[fi*Fout + sub*OPL + q], o[q]);
        o[q] = fmaf(t1v[fi], W6[(FinReal + fi)*Fout + sub*OPL + q], o[q]);
      }
    }
    vstore<OPL>(out + (size_t)i*Fout + sub*OPL, o);
  } else {
    if (sub < Fout){
      float acc = bias ? bias[sub] : 0.f;
      #pragma unroll
      for (int fi = 0; fi < FinReal; ++fi){
        acc = fmaf(t0v[fi], W6[fi*Fout + sub], acc);
        acc = fmaf(t1v[fi], W6[(FinReal + fi)*Fout + sub], acc);
      }
      out[(size_t)i*Fout + sub] = acc;
    }
  }
}

template<int FinPad, int FinReal, int Fout>
__global__ void k_cheb4_step(const int* __restrict__ rp, const int* __restrict__ srcs,
                             const float* __restrict__ w,
                             const float* __restrict__ Tm1, const float* __restrict__ Tm2,
                             float* __restrict__ Tk, float* __restrict__ out,
                             const float* __restrict__ Wk,
                             int G, int N, int relu){
  constexpr int FPL = FinPad/4;
  long long i4 = swz_i(G);
  if (i4 >= (long long)G*N*4) return;
  int sub = (int)(i4 & 3);
  long long i = i4 >> 2;
  int n = (int)(i % N);
  const float* gb = Tm1 + (size_t)(i - n)*FinPad;
  float tr[FPL];
  #pragma unroll
  for (int q = 0; q < FPL; ++q) tr[q] = 0.f;
  int j0 = rp[n], j1 = rp[n+1];
  for (int j = j0; j < j1; j += 4){
    i32x4 s4 = *reinterpret_cast<const i32x4*>(srcs + j);
    f32x4 w4 = *reinterpret_cast<const f32x4*>(w + j);
    float v0[FPL], v1[FPL], v2[FPL], v3[FPL];
    vload<FPL>(gb + (size_t)s4.x*FinPad + sub*FPL, v0);
    vload<FPL>(gb + (size_t)s4.y*FinPad + sub*FPL, v1);
    vload<FPL>(gb + (size_t)s4.z*FinPad + sub*FPL, v2);
    vload<FPL>(gb + (size_t)s4.w*FinPad + sub*FPL, v3);
    #pragma unroll
    for (int q = 0; q < FPL; ++q){
      tr[q] = fmaf(w4.x, v0[q], tr[q]);
      tr[q] = fmaf(w4.y, v1[q], tr[q]);
      tr[q] = fmaf(w4.z, v2[q], tr[q]);
      tr[q] = fmaf(w4.w, v3[q], tr[q]);
    }
  }
  float t2[FPL];
  vload<FPL>(Tm2 + (size_t)i*FinPad + sub*FPL, t2);
  #pragma unroll
  for (int q = 0; q < FPL; ++q) tr[q] = 2.f*tr[q] - t2[q];
  vstore<FPL>(Tk + (size_t)i*FinPad + sub*FPL, tr);
  float trv[FinPad];
  int base = (int)(threadIdx.x & 63) & ~3;
  #pragma unroll
  for (int s = 0; s < 4; ++s){
    #pragma unroll
    for (int q = 0; q < FPL; ++q)
      trv[s*FPL+q] = __shfl(tr[q], base + s, 64);
  }
  if constexpr (Fout % 4 == 0){
    constexpr int OPL = Fout/4;
    float o[OPL];
    vload<OPL>(out + (size_t)i*Fout + sub*OPL, o);
    #pragma unroll
    for (int fi = 0; fi < FinReal; ++fi){
      #pragma unroll
      for (int q = 0; q < OPL; ++q)
        o[q] = fmaf(trv[fi], Wk[fi*Fout + sub*OPL + q], o[q]);
    }
    if (relu){
      #pragma unroll
      for (int q = 0; q < OPL; ++q) o[q] = fmaxf(o[q], 0.f);
    }
    vstore<OPL>(out + (size_t)i*Fout + sub*OPL, o);
  } else {
    if (sub < Fout){
      float acc = out[(size_t)i*Fout + sub];
      #pragma unroll
      for (int fi = 0; fi < FinReal; ++fi)
        acc = fmaf(trv[fi], Wk[fi*Fout + sub], acc);
      if (relu) acc = fmaxf(acc, 0.f);
      out[(size_t)i*Fout + sub] = acc;
    }
  }
}

// ---------------- old lane-per-row Cheb kernels (N=256 levels) ----------------

template<int Fin, int Fout>
__global__ void k_cheb_first(const int* __restrict__ rp, const int* __restrict__ srcs,
                             const float* __restrict__ w,
                             const float* __restrict__ X, float* __restrict__ T1,
                             float* __restrict__ out,
                             const float* __restrict__ W6, const float* __restrict__ bias,
                             int G, int N){
  long long i = swz_i(G);
  if (i >= (long long)G*N) return;
  int n = (int)(i % N);
  const float* xb = X + (size_t)(i - n)*Fin;
  float t0r[Fin], t1r[Fin];
  loadrow<Fin>(X + (size_t)i*Fin, t0r);
  #pragma unroll
  for (int f = 0; f < Fin; ++f) t1r[f] = 0.f;
  int j0 = rp[n], j1 = rp[n+1];
  for (int j = j0; j < j1; ++j){
    float ww = w[j];
    const float* sr = xb + (size_t)srcs[j]*Fin;
    #pragma unroll
    for (int f = 0; f < Fin; ++f) t1r[f] = fmaf(ww, sr[f], t1r[f]);
  }
  storerow<Fin>(T1 + (size_t)i*Fin, t1r);
  float o[Fout];
  #pragma unroll
  for (int fo = 0; fo < Fout; ++fo) o[fo] = bias ? bias[fo] : 0.f;
  #pragma unroll
  for (int fi = 0; fi < Fin; ++fi){
    #pragma unroll
    for (int fo = 0; fo < Fout; ++fo){
      o[fo] = fmaf(t0r[fi], W6[fi*Fout + fo], o[fo]);
      o[fo] = fmaf(t1r[fi], W6[(Fin + fi)*Fout + fo], o[fo]);
    }
  }
  storerow<Fout>(out + (size_t)i*Fout, o);
}

template<int Fin, int Fout>
__global__ void k_cheb_step(const int* __restrict__ rp, const int* __restrict__ srcs,
                            const float* __restrict__ w,
                            const float* __restrict__ Tm1, const float* __restrict__ Tm2,
                            float* __restrict__ Tk, float* __restrict__ out,
                            const float* __restrict__ Wk,
                            int G, int N, int relu){
  long long i = swz_i(G);
  if (i >= (long long)G*N) return;
  int n = (int)(i % N);
  const float* xb = Tm1 + (size_t)(i - n)*Fin;
  float tr[Fin];
  #pragma unroll
  for (int f = 0; f < Fin; ++f) tr[f] = 0.f;
  int j0 = rp[n], j1 = rp[n+1];
  for (int j = j0; j < j1; ++j){
    float ww = w[j];
    const float* sr = xb + (size_t)srcs[j]*Fin;
    #pragma unroll
    for (int f = 0; f < Fin; ++f) tr[f] = fmaf(ww, sr[f], tr[f]);
  }
  float t2r[Fin];
  loadrow<Fin>(Tm2 + (size_t)i*Fin, t2r);
  #pragma unroll
  for (int f = 0; f < Fin; ++f) tr[f] = 2.f*tr[f] - t2r[f];
  storerow<Fin>(Tk + (size_t)i*Fin, tr);
  float o[Fout];
  loadrow<Fout>(out + (size_t)i*Fout, o);
  #pragma unroll
  for (int fi = 0; fi < Fin; ++fi){
    #pragma unroll
    for (int fo = 0; fo < Fout; ++fo)
      o[fo] = fmaf(tr[fi], Wk[fi*Fout + fo], o[fo]);
  }
  if (relu){
    #pragma unroll
    for (int fo = 0; fo < Fout; ++fo) o[fo] = fmaxf(o[fo], 0.f);
  }
  storerow<Fout>(out + (size_t)i*Fout, o);
}

// ---------------- other model kernels ----------------

// x: [2,16,N,3] -> h8: [32,N,8] padded (last 2 = 0)
__global__ void k_phase_enc8(const float* __restrict__ x, float* __restrict__ h, int N){
  int i = blockIdx.x*blockDim.x + threadIdx.x;
  if (i >= 32*N) return;
  int n = i % N, g = i / N;
  int t = g & 15;
  float th = 6.283185307179586f * (float)t / 16.0f;
  float s, c;
  sincosf(th, &s, &c);
  const float* xr = x + ((size_t)g*N + n)*3;
  float a0 = xr[0], a1 = xr[1], a2 = xr[2];
  float hr[8] = {a0*c, a1*c, a2*c, a0*s, a1*s, a2*s, 0.f, 0.f};
  storerow<8>(h + ((size_t)g*N + n)*8, hr);
}

template<int F>
__global__ void k_pool_t(const float* __restrict__ X, const int* __restrict__ idx,
                         const float* __restrict__ w, float* __restrict__ out,
                         int G, int Nin, int Nout){
  long long i = swz_i(G);
  if (i >= (long long)G*Nout) return;
  int n = (int)(i % Nout), g = (int)(i / Nout);
  int i0 = idx[n*3+0], i1 = idx[n*3+1], i2 = idx[n*3+2];
  float w0 = w[n*3+0], w1 = w[n*3+1], w2 = w[n*3+2];
  const float* b = X + (size_t)g*Nin*F;
  float r0[F], r1[F], r2[F], o[F];
  loadrow<F>(b + (size_t)i0*F, r0);
  loadrow<F>(b + (size_t)i1*F, r1);
  loadrow<F>(b + (size_t)i2*F, r2);
  #pragma unroll
  for (int f = 0; f < F; ++f)
    o[f] = fmaf(w0, r0[f], fmaf(w1, r1[f], w2 * r2[f]));
  storerow<F>(out + ((size_t)g*Nout + n)*F, o);
}

// mu: one wave per (g,z), coalesced + shuffle reduce
__global__ void k_mu(const float* __restrict__ h, const float* __restrict__ W,
                     const float* __restrict__ b, float* __restrict__ mu){
  int wid = (blockIdx.x*blockDim.x + threadIdx.x) >> 6;
  int lane = threadIdx.x & 63;
  if (wid >= 32*48) return;
  int z = wid % 48, g = wid / 48;
  const float* hr = h + (size_t)g*2048;
  const float* wr = W + (size_t)z*2048;
  float acc = 0.f;
  for (int f = lane; f < 2048; f += 64) acc = fmaf(hr[f], wr[f], acc);
  for (int o = 32; o > 0; o >>= 1) acc += __shfl_down(acc, o, 64);
  if (lane == 0) mu[wid] = acc + b[z];
}

__global__ void k_mucs(const float* __restrict__ mu, float* __restrict__ muc,
                       float* __restrict__ mus, float* __restrict__ out){
  int i = blockIdx.x*blockDim.x + threadIdx.x;
  if (i >= 96) return;
  int z = i % 48, bp = i / 48;
  float acc = 0.f;
  for (int b = 0; b < 2; ++b)
    for (int t = 8*bp; t < 8*bp + 8; ++t)
      acc += mu[(b*16 + t)*48 + z];
  acc *= (1.f/16.f);
  if (z < 32){ muc[bp*32 + z] = acc; out[bp*32 + z] = acc; }
  else       { mus[bp*16 + (z-32)] = acc; out[64 + bp*16 + (z-32)] = acc; }
}

__global__ void k_zin(const float* __restrict__ muc, const float* __restrict__ mus,
                      float* __restrict__ zin){
  int i = blockIdx.x*blockDim.x + threadIdx.x;
  if (i >= 32*64) return;
  int c = i % 64, g = i / 64;
  int b = g / 16, t = g % 16;
  float v;
  if (c < 32){
    v = muc[b*32 + c];
  } else {
    float th = 6.283185307179586f * (float)t / 16.0f;
    int k = c - 32;
    int kk = (k < 16) ? k : (k - 16);
    float m = mus[b*16 + kk];
    v = (k < 16) ? m * cosf(th) : m * sinf(th);
  }
  zin[i] = v;
}

__global__ void k_lin(const float* __restrict__ z, const float* __restrict__ W,
                      const float* __restrict__ b, float* __restrict__ y,
                      int G, int Z, int relu){
  int i = blockIdx.x*blockDim.x + threadIdx.x;
  if (i >= G*2048) return;
  int f = i % 2048, g = i / 2048;
  const float* zr = z + (size_t)g*Z;
  const float* wr = W + (size_t)f*Z;
  float acc = b[f];
  for (int k = 0; k < Z; ++k) acc = fmaf(zr[k], wr[k], acc);
  if (relu) acc = fmaxf(acc, 0.f);
  y[i] = acc;
}

__global__ void k_st(const float* __restrict__ savg, const float* __restrict__ ds,
                     float* __restrict__ st, int N){
  int i = blockIdx.x*blockDim.x + threadIdx.x;
  if (i >= 32*N*3) return;
  int c = i % (N*3);
  int g = i / (N*3);
  int b = g >> 4;
  st[i] = savg[(size_t)b*N*3 + c] + ds[i];
}

// ---------------- host orchestration ----------------

struct Csr { const int* rp; const int* srcs; const float* w; };

static void launch4_first(hipStream_t s, int FinPad, int Fout, const Csr& A,
                          const float* X, float* T1, float* out,
                          const float* W6, const float* bias, int G, int N){
  long long GN4 = (long long)G*N*4;
  dim3 gr(cdiv(GN4,TPB)), bl(TPB);
  if      (FinPad == 8) k_cheb4_first<8,6,16><<<gr,bl,0,s>>>(A.rp,A.srcs,A.w,X,T1,out,W6,bias,G,N);
  else if (Fout == 16)  k_cheb4_first<16,16,16><<<gr,bl,0,s>>>(A.rp,A.srcs,A.w,X,T1,out,W6,bias,G,N);
  else                  k_cheb4_first<16,16,3><<<gr,bl,0,s>>>(A.rp,A.srcs,A.w,X,T1,out,W6,bias,G,N);
}

static void launch4_step(hipStream_t s, int FinPad, int Fout, const Csr& A,
                         const float* Tm1, const float* Tm2, float* Tk, float* out,
                         const float* Wk, int G, int N, int relu){
  long long GN4 = (long long)G*N*4;
  dim3 gr(cdiv(GN4,TPB)), bl(TPB);
  if      (FinPad == 8) k_cheb4_step<8,6,16><<<gr,bl,0,s>>>(A.rp,A.srcs,A.w,Tm1,Tm2,Tk,out,Wk,G,N,relu);
  else if (Fout == 16)  k_cheb4_step<16,16,16><<<gr,bl,0,s>>>(A.rp,A.srcs,A.w,Tm1,Tm2,Tk,out,Wk,G,N,relu);
  else                  k_cheb4_step<16,16,3><<<gr,bl,0,s>>>(A.rp,A.srcs,A.w,Tm1,Tm2,Tk,out,Wk,G,N,relu);
}

static void run_cheb4(hipStream_t s, const Csr& A, int N, int G,
                      float* X, float* T1, float* S, float* out,
                      const float* W6, const float* bias,
                      int FinPad, int FinReal, int Fout, bool relu){
  launch4_first(s, FinPad, Fout, A, X, T1, out, W6, bias, G, N);
  float* t0 = X; float* t1 = T1; float* sp = S;
  for (int k = 2; k < 6; ++k){
    int last = (k == 5 && relu) ? 1 : 0;
    launch4_step(s, FinPad, Fout, A, t1, t0, sp, out, W6 + (size_t)k*FinReal*Fout, G, N, last);
    float* tmp = t0; t0 = t1; t1 = sp; sp = tmp;
  }
}

static void run_cheb_old(hipStream_t s, const Csr& A, int N, int G,
                         float* X, float* T1, float* S, float* out,
                         const float* W6, const float* bias, int Fin, int Fout, bool relu){
  long long GN = (long long)G*N;
  dim3 gr(cdiv(GN,TPB)), bl(TPB);
  if (Fin == 16)
    k_cheb_first<16,32><<<gr,bl,0,s>>>(A.rp,A.srcs,A.w,X,T1,out,W6,bias,G,N);
  else
    k_cheb_first<32,16><<<gr,bl,0,s>>>(A.rp,A.srcs,A.w,X,T1,out,W6,bias,G,N);
  float* t0 = X; float* t1 = T1; float* sp = S;
  for (int k = 2; k < 6; ++k){
    int last = (k == 5 && relu) ? 1 : 0;
    if (Fin == 16)
      k_cheb_step<16,32><<<gr,bl,0,s>>>(A.rp,A.srcs,A.w,t1,t0,sp,out,W6 + (size_t)k*Fin*Fout,G,N,last);
    else
      k_cheb_step<32,16><<<gr,bl,0,s>>>(A.rp,A.srcs,A.w,t1,t0,sp,out,W6 + (size_t)k*Fin*Fout,G,N,last);
    float* tmp = t0; t0 = t1; t1 = sp; sp = tmp;
  }
}

static void launch_pool(hipStream_t s, int F, const float* X, const int* idx,
                        const float* w, float* out, int G, int Nin, int Nout){
  long long GNo = (long long)G*Nout;
  dim3 gr(cdiv(GNo,TPB)), bl(TPB);
  if (F == 16) k_pool_t<16><<<gr,bl,0,s>>>(X, idx, w, out, G, Nin, Nout);
  else         k_pool_t<32><<<gr,bl,0,s>>>(X, idx, w, out, G, Nin, Nout);
}

static void run_dec(hipStream_t s, int G, const float* z, int Z,
                    const float* lW, const float* lb, bool relu_first,
                    const float* const* W, const float* const* Bc,
                    const Csr* A, const int* const* us_i, const float* const* us_w,
                    float* B0, float* B1, float* B2, float* B3, float* out_final){
  k_lin<<<cdiv((long long)G*2048,TPB),TPB,0,s>>>(z, lW, lb, B0, G, Z, relu_first ? 1 : 0);
  launch_pool(s, 32, B0, us_i[3], us_w[3], B1, G, 64, 256);
  run_cheb_old(s, A[3], 256, G, B1, B0, B2, B3, W[0], Bc[0], 32, 16, true);
  launch_pool(s, 16, B3, us_i[2], us_w[2], B0, G, 256, 1024);
  run_cheb4(s, A[2], 1024, G, B0, B1, B2, B3, W[1], Bc[1], 16, 16, 16, true);
  launch_pool(s, 16, B3, us_i[1], us_w[1], B0, G, 1024, 4096);
  run_cheb4(s, A[1], 4096, G, B0, B1, B2, B3, W[2], Bc[2], 16, 16, 16, true);
  launch_pool(s, 16, B3, us_i[0], us_w[0], B0, G, 4096, 16384);
  run_cheb4(s, A[4], 16384, G, B0, B1, B2, out_final, W[3], nullptr, 16, 16, 3, false);
}

extern "C" void kernel_launch(void* const* d_in, const int* in_sizes, int n_in,
                              void* d_out, int out_size, void* d_ws, size_t ws_size,
                              hipStream_t stream){
  const float* x = (const float*)d_in[0];
  const float* encW[4] = {(const float*)d_in[1],(const float*)d_in[3],(const float*)d_in[5],(const float*)d_in[7]};
  const float* encB[4] = {(const float*)d_in[2],(const float*)d_in[4],(const float*)d_in[6],(const float*)d_in[8]};
  const float* ccW[4]  = {(const float*)d_in[9],(const float*)d_in[11],(const float*)d_in[13],(const float*)d_in[15]};
  const float* ccB[3]  = {(const float*)d_in[10],(const float*)d_in[12],(const float*)d_in[14]};
  const float* csW[4]  = {(const float*)d_in[16],(const float*)d_in[18],(const float*)d_in[20],(const float*)d_in[22]};
  const float* csB[3]  = {(const float*)d_in[17],(const float*)d_in[19],(const float*)d_in[21]};
  const float* muW  = (const float*)d_in[23]; const float* muB  = (const float*)d_in[24];
  const float* lincW = (const float*)d_in[25]; const float* lincB = (const float*)d_in[26];
  const float* linsW = (const float*)d_in[27]; const float* linsB = (const float*)d_in[28];
  const int* ei[5] = {(const int*)d_in[29],(const int*)d_in[30],(const int*)d_in[31],
                      (const int*)d_in[32],(const int*)d_in[33]};
  const int* ds_i[4]; const float* ds_w[4]; const int* us_i[4]; const float* us_w[4];
  for (int l = 0; l < 4; ++l){
    ds_i[l] = (const int*)d_in[34 + 4*l]; ds_w[l] = (const float*)d_in[35 + 4*l];
    us_i[l] = (const int*)d_in[36 + 4*l]; us_w[l] = (const float*)d_in[37 + 4*l];
  }

  float* ws = (float*)d_ws;
  const size_t BIG = 8388608;   // 32*16384*16 floats
  float* B0 = ws + 0*BIG;
  float* B1 = ws + 1*BIG;
  float* B2 = ws + 2*BIG;
  float* B3 = ws + 3*BIG;
  size_t off = 4*BIG;
  auto align4 = [&](){ off = (off + 3) & ~(size_t)3; };

  int Es[5] = {196608, 49152, 12288, 3072, 196608};
  int Nn[5] = {16384, 4096, 1024, 256, 16384};

  // CSR storage per level (rows padded to x4 -> up to E + 4N entries)
  int* rp[5]; int* cursor[5]; int* srcs[5]; float* wcsr[5]; int csrcap[5];
  for (int l = 0; l < 5; ++l){
    csrcap[l] = Es[l] + 4*Nn[l];
    align4(); rp[l]     = (int*)(ws + off); off += (size_t)Nn[l] + 1;
    align4(); cursor[l] = (int*)(ws + off); off += (size_t)Nn[l] + 1;
    align4(); srcs[l]   = (int*)(ws + off); off += (size_t)csrcap[l];
    align4(); wcsr[l]   =        ws + off;  off += (size_t)csrcap[l];
  }
  align4();
  int* rowdeg = (int*)(ws + off); off += 16384;
  int* dstdeg = (int*)(ws + off); off += 16384;
  float* dis  = ws + off; off += 16384;
  float* hmu = ws + off; off += (size_t)32*2048;
  float* mu  = ws + off; off += (size_t)32*48;
  float* muc = ws + off; off += 64;
  float* mus = ws + off; off += 32;
  float* zin = ws + off; off += (size_t)32*64;

  float* outp = (float*)d_out;
  float* out_savg = outp + 96;         // [2,16384,3]
  float* out_st   = outp + 96 + 98304; // [2,16,16384,3]

  // ---- CSR build per level (zero srcs/w so pad slots are inert) ----
  for (int l = 0; l < 5; ++l){
    hipMemsetAsync(rowdeg, 0, (size_t)Nn[l]*sizeof(int), stream);
    hipMemsetAsync(dstdeg, 0, (size_t)Nn[l]*sizeof(int), stream);
    hipMemsetAsync(srcs[l], 0, (size_t)csrcap[l]*sizeof(int), stream);
    hipMemsetAsync(wcsr[l], 0, (size_t)csrcap[l]*sizeof(float), stream);
    k_degs<<<cdiv(Es[l],TPB),TPB,0,stream>>>(ei[l], rowdeg, dstdeg, Es[l]);
    k_dis<<<cdiv(Nn[l],TPB),TPB,0,stream>>>(rowdeg, dis, Nn[l]);
    k_scan<<<1,256,0,stream>>>(dstdeg, rp[l], cursor[l], Nn[l]);
    k_fill<<<cdiv(Es[l],TPB),TPB,0,stream>>>(ei[l], dis, cursor[l], srcs[l], wcsr[l], Es[l]);
  }
  Csr A[5];
  for (int l = 0; l < 5; ++l) A[l] = Csr{rp[l], srcs[l], wcsr[l]};

  // ---- encoder ----
  k_phase_enc8<<<cdiv((long long)32*16384,TPB),TPB,0,stream>>>(x, B0, 16384);
  run_cheb4(stream, A[0], 16384, 32, B0, B1, B2, B3, encW[0], encB[0], 8, 6, 16, true);
  launch_pool(stream, 16, B3, ds_i[0], ds_w[0], B0, 32, 16384, 4096);
  run_cheb4(stream, A[1], 4096, 32, B0, B1, B2, B3, encW[1], encB[1], 16, 16, 16, true);
  launch_pool(stream, 16, B3, ds_i[1], ds_w[1], B0, 32, 4096, 1024);
  run_cheb4(stream, A[2], 1024, 32, B0, B1, B2, B3, encW[2], encB[2], 16, 16, 16, true);
  launch_pool(stream, 16, B3, ds_i[2], ds_w[2], B0, 32, 1024, 256);
  run_cheb_old(stream, A[3], 256, 32, B0, B1, B2, B3, encW[3], encB[3], 16, 32, true);
  launch_pool(stream, 32, B3, ds_i[3], ds_w[3], hmu, 32, 256, 64);

  // ---- latent ----
  k_mu<<<cdiv((long long)32*48*64,TPB),TPB,0,stream>>>(hmu, muW, muB, mu);
  k_mucs<<<1,128,0,stream>>>(mu, muc, mus, outp);

  // ---- decoder c (G=2) -> s_avg in d_out ----
  run_dec(stream, 2, muc, 32, lincW, lincB, false, ccW, ccB,
          A, us_i, us_w, B0, B1, B2, B3, out_savg);

  // ---- decoder s (G=32) -> ds_t in B3 ----
  k_zin<<<cdiv(32*64,TPB),TPB,0,stream>>>(muc, mus, zin);
  run_dec(stream, 32, zin, 64, linsW, linsB, true, csW, csB,
          A, us_i, us_w, B0, B1, B2, B3, B3);

  // ---- s_t = s_avg + ds_t ----
  k_st<<<cdiv((long long)32*16384*3,TPB),TPB,0,stream>>>(out_savg, B3, out_st, 16384);

  (void)in_sizes; (void)n_in; (void)out_size; (void)ws_size;
}